// Round 1
// baseline (465.127 us; speedup 1.0000x reference)
//
#include <hip/hip_runtime.h>
#include <hip/hip_bf16.h>

// GCN: out = relu(gcnconv(relu(gcnconv(x,W1,b1)), W2, b2)) @ Wfc + bfc
// N=50000, E=800000, F0=100, F1=256, F2=128. All-fp32 value path (bf16 blows
// the ~6e-6 relative threshold — round-4 post-mortem).
// Round 11: layer-2 aggregation rebuilt as XCD-pinned feature-chunked gather.
// h2 table stored chunk-major [8][n][16] (one 64B line per row-chunk); chunk c
// is processed only by blocks with blockIdx%8==c, which land on XCD c
// (round-robin dispatch) -> each XCD gathers from a private 3.2 MB slice that
// fits its 4 MB L2. csr read nontemporal to avoid polluting the resident
// table. Baseline pull_f128_fused was fabric-bound: 228 MB FETCH @3.5 TB/s.

#define F0 100
#define F1 256
#define F2 128

// ---------------- CSR construction ----------------

__global__ void zero_i32(int* p, int n) {
    int i = blockIdx.x * blockDim.x + threadIdx.x;
    if (i < n) p[i] = 0;
}

// out[i] = bfc (pre-fill so chunk passes can atomicAdd without ordering)
__global__ void fill_f32(float* out, const float* __restrict__ bfc, int n) {
    int i = blockIdx.x * blockDim.x + threadIdx.x;
    if (i < n) out[i] = bfc[0];
}

__global__ void deg_count_i(const int* __restrict__ dst, int* deg, int e) {
    int i = blockIdx.x * blockDim.x + threadIdx.x;
    if (i < e) atomicAdd(deg + dst[i], 1);
}

// per-block exclusive scan of deg + block sums; also emits dinv = rsqrt(deg+1)
__global__ __launch_bounds__(256) void scan1(const int* __restrict__ deg,
                                             int* __restrict__ excl,
                                             int* __restrict__ bsum,
                                             float* __restrict__ dinv, int n) {
    __shared__ int wsum[4];
    int i = blockIdx.x * 256 + threadIdx.x;
    int lane = threadIdx.x & 63, wid = threadIdx.x >> 6;
    int v = (i < n) ? deg[i] : 0;
    if (i < n) dinv[i] = rsqrtf((float)(v + 1));
    int s = v;
#pragma unroll
    for (int off = 1; off < 64; off <<= 1) {
        int t = __shfl_up(s, off, 64);
        if (lane >= off) s += t;
    }
    if (lane == 63) wsum[wid] = s;
    __syncthreads();
    int add = 0;
    for (int w = 0; w < wid; w++) add += wsum[w];
    if (i < n) excl[i] = add + s - v;
    if (threadIdx.x == 255) bsum[blockIdx.x] = add + s;
}

__global__ __launch_bounds__(256) void scan2(int* __restrict__ bsum, int nb,
                                             int* __restrict__ rowptr, int n) {
    __shared__ int wsum[4];
    int lane = threadIdx.x & 63, wid = threadIdx.x >> 6;
    int v = (threadIdx.x < nb) ? bsum[threadIdx.x] : 0;
    int s = v;
#pragma unroll
    for (int off = 1; off < 64; off <<= 1) {
        int t = __shfl_up(s, off, 64);
        if (lane >= off) s += t;
    }
    if (lane == 63) wsum[wid] = s;
    __syncthreads();
    int add = 0;
    for (int w = 0; w < wid; w++) add += wsum[w];
    if (threadIdx.x < nb) bsum[threadIdx.x] = add + s - v;
    if (threadIdx.x == 255) rowptr[n] = add + s;
}

__global__ void scan3(const int* __restrict__ excl, const int* __restrict__ bsum,
                      int* __restrict__ rowptr, int* __restrict__ cursor, int n) {
    int i = blockIdx.x * 256 + threadIdx.x;
    if (i < n) {
        int r = excl[i] + bsum[blockIdx.x];
        rowptr[i] = r;
        cursor[i] = r;
    }
}

__global__ void csr_fill(const int* __restrict__ src, const int* __restrict__ dst,
                         int* cursor, int* __restrict__ csr, int e) {
    int i = blockIdx.x * blockDim.x + threadIdx.x;
    if (i < e) {
        int pos = atomicAdd(cursor + dst[i], 1);
        csr[pos] = src[i];
    }
}

// xs = dinv[row] * x, row = float4-index / 25 (100 floats = 25 float4)
__global__ void scale_x(const float4* __restrict__ x4,
                        const float* __restrict__ dinv,
                        float4* __restrict__ xs4, int n25) {
    int i = blockIdx.x * blockDim.x + threadIdx.x;
    if (i < n25) {
        float d = dinv[i / 25];
        float4 v = x4[i];
        v.x *= d; v.y *= d; v.z *= d; v.w *= d;
        xs4[i] = v;
    }
}

// ---------------- pull-gather aggregation (pre-scaled tables) --------------

// agg[v][:] = dinv[v] * sum_{s in in(v) ∪ {v}} xs[s][:]
// One wave/node. Row = 25 float4. Lanes 0-24 even edges, 32-56 odd edges.
__global__ __launch_bounds__(256) void pull_f100(
        const float* __restrict__ xs, const int* __restrict__ rowptr,
        const int* __restrict__ csr, const float* __restrict__ dinv,
        float* __restrict__ agg, int n) {
    int wave = threadIdx.x >> 6, lane = threadIdx.x & 63;
    int v = blockIdx.x * 4 + wave;
    if (v >= n) return;
    int beg = rowptr[v], end = rowptr[v + 1];
    float dv = dinv[v];
    int half = lane >> 5, q = lane & 31;
    bool act = q < 25;
    float4 acc = {0.f, 0.f, 0.f, 0.f};
    if (half == 0 && act) acc = ((const float4*)(xs + (size_t)v * F0))[q];  // self

    for (int base = beg; base < end; base += 64) {
        int cnt = min(64, end - base);
        int sidx = (lane < cnt) ? csr[base + lane] : 0;
        int npf = cnt >> 1;
        int p = 0;
        for (; p + 4 <= npf; p += 4) {
            int s0 = __shfl(sidx, 2 * p + half, 64);
            int s1 = __shfl(sidx, 2 * p + 2 + half, 64);
            int s2 = __shfl(sidx, 2 * p + 4 + half, 64);
            int s3 = __shfl(sidx, 2 * p + 6 + half, 64);
            if (act) {
                float4 r0 = ((const float4*)(xs + (size_t)s0 * F0))[q];
                float4 r1 = ((const float4*)(xs + (size_t)s1 * F0))[q];
                float4 r2 = ((const float4*)(xs + (size_t)s2 * F0))[q];
                float4 r3 = ((const float4*)(xs + (size_t)s3 * F0))[q];
                acc.x += (r0.x + r1.x) + (r2.x + r3.x);
                acc.y += (r0.y + r1.y) + (r2.y + r3.y);
                acc.z += (r0.z + r1.z) + (r2.z + r3.z);
                acc.w += (r0.w + r1.w) + (r2.w + r3.w);
            }
        }
        for (; p < npf; p++) {
            int s0 = __shfl(sidx, 2 * p + half, 64);
            if (act) {
                float4 r0 = ((const float4*)(xs + (size_t)s0 * F0))[q];
                acc.x += r0.x; acc.y += r0.y; acc.z += r0.z; acc.w += r0.w;
            }
        }
        if (cnt & 1) {
            int sl = __shfl(sidx, cnt - 1, 64);
            if (half == 0 && act) {
                float4 r = ((const float4*)(xs + (size_t)sl * F0))[q];
                acc.x += r.x; acc.y += r.y; acc.z += r.z; acc.w += r.w;
            }
        }
    }
    float ox = __shfl_down(acc.x, 32, 64);
    float oy = __shfl_down(acc.y, 32, 64);
    float oz = __shfl_down(acc.z, 32, 64);
    float ow = __shfl_down(acc.w, 32, 64);
    if (half == 0 && act) {
        float4 r;
        r.x = dv * (acc.x + ox);
        r.y = dv * (acc.y + oy);
        r.z = dv * (acc.z + oz);
        r.w = dv * (acc.w + ow);
        ((float4*)(agg + (size_t)v * F0))[q] = r;
    }
}

// Layer-2 fused aggregation, XCD-pinned feature chunks.
// h2c layout: [8][n][16] chunk-major, rows pre-scaled by dinv[row] (gemm2).
// chunk = blockIdx.x & 7  ->  lands on XCD (blockIdx % 8) => each XCD's L2
// only ever sees its own contiguous 3.2 MB chunk slice (fits 4 MB L2).
// Wave = 1 node: 16 quads x 4 lanes, one 64 B row-chunk per quad (16 edges
// in flight per load instruction). Butterfly xor-reduce across quads, then
// relu(dv*agg + b2)·Wfc partial dot, atomicAdd into bfc-prefilled out.
__global__ __launch_bounds__(256) void pull_c16_fused(
        const float* __restrict__ h2c, const int* __restrict__ rowptr,
        const int* __restrict__ csr, const float* __restrict__ dinv,
        const float* __restrict__ b2, const float* __restrict__ Wfc,
        float* __restrict__ out, int n) {
    int chunk = blockIdx.x & 7;
    int nb = blockIdx.x >> 3;
    int wave = threadIdx.x >> 6, lane = threadIdx.x & 63;
    int v = nb * 4 + wave;
    if (v >= n) return;
    int beg = rowptr[v], end = rowptr[v + 1];
    float dv = dinv[v];
    int q = lane & 3;      // float4 slot within the 16-float chunk row
    int g = lane >> 2;     // quad id: which edge of the group of 16
    const float* __restrict__ tab = h2c + (size_t)chunk * n * 16;

    float4 acc = {0.f, 0.f, 0.f, 0.f};
    if (g == 0) acc = ((const float4*)(tab + (size_t)v * 16))[q];  // self

    for (int base = beg; base < end; base += 64) {
        int cnt = min(64, end - base);
        // nontemporal: don't let the csr stream evict the resident table
        int sidx = (lane < cnt) ? __builtin_nontemporal_load(csr + base + lane) : 0;
        int iters = (cnt + 15) >> 4;
        for (int it = 0; it < iters; ++it) {
            int e = (it << 4) + g;            // e <= 63 always
            int s = __shfl(sidx, e, 64);
            if (e < cnt) {
                float4 r = ((const float4*)(tab + (size_t)s * 16))[q];
                acc.x += r.x; acc.y += r.y; acc.z += r.z; acc.w += r.w;
            }
        }
    }
    // reduce across 16 quads (butterfly): every lane ends with full agg[q]
#pragma unroll
    for (int off = 4; off < 64; off <<= 1) {
        acc.x += __shfl_xor(acc.x, off, 64);
        acc.y += __shfl_xor(acc.y, off, 64);
        acc.z += __shfl_xor(acc.z, off, 64);
        acc.w += __shfl_xor(acc.w, off, 64);
    }
    int c0 = chunk * 16 + 4 * q;
    float4 bb = *(const float4*)(b2 + c0);
    float4 ww = *(const float4*)(Wfc + c0);
    float part = fmaxf(fmaf(dv, acc.x, bb.x), 0.f) * ww.x
               + fmaxf(fmaf(dv, acc.y, bb.y), 0.f) * ww.y
               + fmaxf(fmaf(dv, acc.z, bb.z), 0.f) * ww.z
               + fmaxf(fmaf(dv, acc.w, bb.w), 0.f) * ww.w;
    part += __shfl_xor(part, 1, 64);
    part += __shfl_xor(part, 2, 64);
    if (lane == 0) atomicAdd(out + v, part);
}

// ---------------- dense transforms (fp32, 128x128 tile, 8x8 micro) --------
// Direct LDS staging (NO register prefetch — round-9 occupancy cliff).

// C = relu(A @ W + bias), A:[n,100], W:[100,256]. K chunked by 20.
__global__ __launch_bounds__(256) void gemm1_tiled(
        const float* __restrict__ A, const float* __restrict__ W,
        const float* __restrict__ bias, float* __restrict__ C, int n) {
    __shared__ float As[20 * 128];
    __shared__ float Bs[20 * 128];
    int tid = threadIdx.x;
    int r0 = blockIdx.x * 128;
    int c0 = blockIdx.y * 128;
    int tc = tid & 15, tr = tid >> 4;
    float acc[8][8] = {};

    for (int k0 = 0; k0 < F0; k0 += 20) {
        if (k0) __syncthreads();
        for (int idx = tid; idx < 128 * 5; idx += 256) {
            int row = idx & 127, kq = idx >> 7;
            int gr = r0 + row;
            if (gr >= n) gr = n - 1;
            float4 v = *(const float4*)(A + (size_t)gr * F0 + k0 + 4 * kq);
            As[(4 * kq + 0) * 128 + row] = v.x;
            As[(4 * kq + 1) * 128 + row] = v.y;
            As[(4 * kq + 2) * 128 + row] = v.z;
            As[(4 * kq + 3) * 128 + row] = v.w;
        }
        for (int idx = tid; idx < 20 * 32; idx += 256) {
            int k = idx >> 5, cq = idx & 31;
            *(float4*)(Bs + k * 128 + 4 * cq) =
                *(const float4*)(W + (size_t)(k0 + k) * F1 + c0 + 4 * cq);
        }
        __syncthreads();
#pragma unroll 5
        for (int k = 0; k < 20; k++) {
            float4 a0 = *(const float4*)(As + k * 128 + 4 * tr);
            float4 a1 = *(const float4*)(As + k * 128 + 64 + 4 * tr);
            float4 b0 = *(const float4*)(Bs + k * 128 + 4 * tc);
            float4 b1 = *(const float4*)(Bs + k * 128 + 64 + 4 * tc);
            float av[8] = {a0.x, a0.y, a0.z, a0.w, a1.x, a1.y, a1.z, a1.w};
            float bv[8] = {b0.x, b0.y, b0.z, b0.w, b1.x, b1.y, b1.z, b1.w};
#pragma unroll
            for (int i = 0; i < 8; i++)
#pragma unroll
                for (int j = 0; j < 8; j++) acc[i][j] += av[i] * bv[j];
        }
    }
    float4 bb0 = *(const float4*)(bias + c0 + 4 * tc);
    float4 bb1 = *(const float4*)(bias + c0 + 64 + 4 * tc);
    float bv[8] = {bb0.x, bb0.y, bb0.z, bb0.w, bb1.x, bb1.y, bb1.z, bb1.w};
#pragma unroll
    for (int i = 0; i < 8; i++) {
        int row = (i < 4) ? (4 * tr + i) : (64 + 4 * tr + i - 4);
        int gr = r0 + row;
        if (gr < n) {
            float4 o0, o1;
            o0.x = fmaxf(acc[i][0] + bv[0], 0.f);
            o0.y = fmaxf(acc[i][1] + bv[1], 0.f);
            o0.z = fmaxf(acc[i][2] + bv[2], 0.f);
            o0.w = fmaxf(acc[i][3] + bv[3], 0.f);
            o1.x = fmaxf(acc[i][4] + bv[4], 0.f);
            o1.y = fmaxf(acc[i][5] + bv[5], 0.f);
            o1.z = fmaxf(acc[i][6] + bv[6], 0.f);
            o1.w = fmaxf(acc[i][7] + bv[7], 0.f);
            *(float4*)(C + (size_t)gr * F1 + c0 + 4 * tc) = o0;
            *(float4*)(C + (size_t)gr * F1 + c0 + 64 + 4 * tc) = o1;
        }
    }
}

// h2c = dinv[row] * (A @ W), A:[n,256], W:[256,128]. 128 rows x full F2, K by 32.
// Epilogue stores CHUNK-MAJOR: h2c[(col>>4)][row][col&15], 64 B per 4 lanes.
__global__ __launch_bounds__(256) void gemm2_tiled(
        const float* __restrict__ A, const float* __restrict__ W,
        const float* __restrict__ dinv, float* __restrict__ C, int n) {
    __shared__ float As[32 * 128];
    __shared__ float Bs[32 * 128];
    int tid = threadIdx.x;
    int r0 = blockIdx.x * 128;
    int tc = tid & 15, tr = tid >> 4;
    float acc[8][8] = {};

    for (int k0 = 0; k0 < F1; k0 += 32) {
        if (k0) __syncthreads();
        for (int idx = tid; idx < 128 * 8; idx += 256) {
            int row = idx & 127, kq = idx >> 7;
            int gr = r0 + row;
            if (gr >= n) gr = n - 1;
            float4 v = *(const float4*)(A + (size_t)gr * F1 + k0 + 4 * kq);
            As[(4 * kq + 0) * 128 + row] = v.x;
            As[(4 * kq + 1) * 128 + row] = v.y;
            As[(4 * kq + 2) * 128 + row] = v.z;
            As[(4 * kq + 3) * 128 + row] = v.w;
        }
        for (int idx = tid; idx < 32 * 32; idx += 256) {
            int k = idx >> 5, cq = idx & 31;
            *(float4*)(Bs + k * 128 + 4 * cq) =
                *(const float4*)(W + (size_t)(k0 + k) * F2 + 4 * cq);
        }
        __syncthreads();
#pragma unroll 4
        for (int k = 0; k < 32; k++) {
            float4 a0 = *(const float4*)(As + k * 128 + 4 * tr);
            float4 a1 = *(const float4*)(As + k * 128 + 64 + 4 * tr);
            float4 b0 = *(const float4*)(Bs + k * 128 + 4 * tc);
            float4 b1 = *(const float4*)(Bs + k * 128 + 64 + 4 * tc);
            float av[8] = {a0.x, a0.y, a0.z, a0.w, a1.x, a1.y, a1.z, a1.w};
            float bv[8] = {b0.x, b0.y, b0.z, b0.w, b1.x, b1.y, b1.z, b1.w};
#pragma unroll
            for (int i = 0; i < 8; i++)
#pragma unroll
                for (int j = 0; j < 8; j++) acc[i][j] += av[i] * bv[j];
        }
    }
    int ch = tc >> 2;             // chunk of columns 4*tc (0..3)
    int of = (tc & 3) << 2;       // float4 offset inside 16-float chunk row
#pragma unroll
    for (int i = 0; i < 8; i++) {
        int row = (i < 4) ? (4 * tr + i) : (64 + 4 * tr + i - 4);
        int gr = r0 + row;
        if (gr < n) {
            float d = dinv[gr];
            float4 o0 = {acc[i][0] * d, acc[i][1] * d, acc[i][2] * d, acc[i][3] * d};
            float4 o1 = {acc[i][4] * d, acc[i][5] * d, acc[i][6] * d, acc[i][7] * d};
            *(float4*)(C + ((size_t)ch * n + gr) * 16 + of) = o0;        // cols 4tc..
            *(float4*)(C + ((size_t)(ch + 4) * n + gr) * 16 + of) = o1;  // cols 64+4tc..
        }
    }
}

// ---------------- launch ----------------

static inline size_t align16(size_t x) { return (x + 3) & ~(size_t)3; }  // in 4B elems

extern "C" void kernel_launch(void* const* d_in, const int* in_sizes, int n_in,
                              void* d_out, int out_size, void* d_ws, size_t ws_size,
                              hipStream_t stream) {
    const float* x   = (const float*)d_in[0];
    const int*   ei  = (const int*)d_in[1];
    const float* W1  = (const float*)d_in[2];
    const float* b1  = (const float*)d_in[3];
    const float* W2  = (const float*)d_in[4];
    const float* b2  = (const float*)d_in[5];
    const float* Wfc = (const float*)d_in[6];
    const float* bfc = (const float*)d_in[7];
    float* out = (float*)d_out;

    const int n = in_sizes[0] / F0;   // 50000
    const int e = in_sizes[1] / 2;    // 800000
    const int* src = ei;
    const int* dst = ei + e;

    // workspace layout (4-byte elements, each region 16B-aligned)
    char* wsb = (char*)d_ws;
    size_t off = 0;
    int* deg    = (int*)(wsb + 4 * off); off = align16(off + n);
    int* excl   = (int*)(wsb + 4 * off); off = align16(off + n);
    int* bsum   = (int*)(wsb + 4 * off); off = align16(off + 256);
    int* rowptr = (int*)(wsb + 4 * off); off = align16(off + n + 1);
    int* cursor = (int*)(wsb + 4 * off); off = align16(off + n);
    int* csr    = (int*)(wsb + 4 * off); off = align16(off + e);
    float* dinv = (float*)(wsb + 4 * off); off = align16(off + n);
    float* xs   = (float*)(wsb + 4 * off); off = align16(off + (size_t)n * F0);
    float* aggX = (float*)(wsb + 4 * off); off = align16(off + (size_t)n * F0);
    float* a1   = (float*)(wsb + 4 * off); off = align16(off + (size_t)n * F1);
    float* h2c  = (float*)(wsb + 4 * off); off = align16(off + (size_t)n * F2);

    const int B = 256;
    const int nb = (n + B - 1) / B;        // 196 (<= 256)
    const int rblocks = (n + 127) / 128;

    // CSR build + scaled-x table; prefill out with bfc for chunked atomics
    zero_i32<<<nb, B, 0, stream>>>(deg, n);
    fill_f32<<<nb, B, 0, stream>>>(out, bfc, n);
    deg_count_i<<<(e + B - 1) / B, B, 0, stream>>>(dst, deg, e);
    scan1<<<nb, B, 0, stream>>>(deg, excl, bsum, dinv, n);
    scale_x<<<((n * 25) + B - 1) / B, B, 0, stream>>>(
        (const float4*)x, dinv, (float4*)xs, n * 25);
    scan2<<<1, B, 0, stream>>>(bsum, nb, rowptr, n);
    scan3<<<nb, B, 0, stream>>>(excl, bsum, rowptr, cursor, n);
    csr_fill<<<(e + B - 1) / B, B, 0, stream>>>(src, dst, cursor, csr, e);

    // layer 1: pull-aggregate xs, then tiled GEMM + bias + relu
    pull_f100<<<(n + 3) / 4, 256, 0, stream>>>(xs, rowptr, csr, dinv, aggX, n);
    gemm1_tiled<<<dim3(rblocks, F1 / 128), 256, 0, stream>>>(aggX, W1, b1, a1, n);

    // layer 2: tiled GEMM -> chunk-major pre-scaled h2c, then XCD-pinned
    // chunked pull + bias + relu + FC (atomic partial dots into out)
    gemm2_tiled<<<rblocks, 256, 0, stream>>>(a1, W2, dinv, h2c, n);
    pull_c16_fused<<<8 * ((n + 3) / 4), 256, 0, stream>>>(
        h2c, rowptr, csr, dinv, b2, Wfc, out, n);
}

// Round 2
// 412.690 us; speedup vs baseline: 1.1271x; 1.1271x over previous
//
#include <hip/hip_runtime.h>
#include <hip/hip_bf16.h>

// GCN: out = relu(gcnconv(relu(gcnconv(x,W1,b1)), W2, b2)) @ Wfc + bfc
// N=50000, E=800000, F0=100, F1=256, F2=128. All-fp32 value path (bf16 blows
// the ~6e-6 relative threshold — round-4 post-mortem).
// Round 12: keep round-11's XCD-pinned chunk-major h2c table ([8][n][16],
// chunk = blockIdx%8 -> private 3.2 MB slice resident in that XCD's 4 MB L2;
// FETCH_SIZE 228 MB -> 26.6 MB, confirmed). Fix round-11's regression
// (147 us: latency-bound, 1 load in flight per wave, 8x per-node overhead):
// now 4 nodes/wave x 4 edge-slots x 4 lanes -> 4 independent 2-deep
// csr->gather chains per node, 2-level butterfly, 100k waves instead of 400k.

#define F0 100
#define F1 256
#define F2 128

// ---------------- CSR construction ----------------

__global__ void zero_i32(int* p, int n) {
    int i = blockIdx.x * blockDim.x + threadIdx.x;
    if (i < n) p[i] = 0;
}

// out[i] = bfc (pre-fill so chunk passes can atomicAdd without ordering)
__global__ void fill_f32(float* out, const float* __restrict__ bfc, int n) {
    int i = blockIdx.x * blockDim.x + threadIdx.x;
    if (i < n) out[i] = bfc[0];
}

__global__ void deg_count_i(const int* __restrict__ dst, int* deg, int e) {
    int i = blockIdx.x * blockDim.x + threadIdx.x;
    if (i < e) atomicAdd(deg + dst[i], 1);
}

// per-block exclusive scan of deg + block sums; also emits dinv = rsqrt(deg+1)
__global__ __launch_bounds__(256) void scan1(const int* __restrict__ deg,
                                             int* __restrict__ excl,
                                             int* __restrict__ bsum,
                                             float* __restrict__ dinv, int n) {
    __shared__ int wsum[4];
    int i = blockIdx.x * 256 + threadIdx.x;
    int lane = threadIdx.x & 63, wid = threadIdx.x >> 6;
    int v = (i < n) ? deg[i] : 0;
    if (i < n) dinv[i] = rsqrtf((float)(v + 1));
    int s = v;
#pragma unroll
    for (int off = 1; off < 64; off <<= 1) {
        int t = __shfl_up(s, off, 64);
        if (lane >= off) s += t;
    }
    if (lane == 63) wsum[wid] = s;
    __syncthreads();
    int add = 0;
    for (int w = 0; w < wid; w++) add += wsum[w];
    if (i < n) excl[i] = add + s - v;
    if (threadIdx.x == 255) bsum[blockIdx.x] = add + s;
}

__global__ __launch_bounds__(256) void scan2(int* __restrict__ bsum, int nb,
                                             int* __restrict__ rowptr, int n) {
    __shared__ int wsum[4];
    int lane = threadIdx.x & 63, wid = threadIdx.x >> 6;
    int v = (threadIdx.x < nb) ? bsum[threadIdx.x] : 0;
    int s = v;
#pragma unroll
    for (int off = 1; off < 64; off <<= 1) {
        int t = __shfl_up(s, off, 64);
        if (lane >= off) s += t;
    }
    if (lane == 63) wsum[wid] = s;
    __syncthreads();
    int add = 0;
    for (int w = 0; w < wid; w++) add += wsum[w];
    if (threadIdx.x < nb) bsum[threadIdx.x] = add + s - v;
    if (threadIdx.x == 255) rowptr[n] = add + s;
}

__global__ void scan3(const int* __restrict__ excl, const int* __restrict__ bsum,
                      int* __restrict__ rowptr, int* __restrict__ cursor, int n) {
    int i = blockIdx.x * 256 + threadIdx.x;
    if (i < n) {
        int r = excl[i] + bsum[blockIdx.x];
        rowptr[i] = r;
        cursor[i] = r;
    }
}

__global__ void csr_fill(const int* __restrict__ src, const int* __restrict__ dst,
                         int* cursor, int* __restrict__ csr, int e) {
    int i = blockIdx.x * blockDim.x + threadIdx.x;
    if (i < e) {
        int pos = atomicAdd(cursor + dst[i], 1);
        csr[pos] = src[i];
    }
}

// xs = dinv[row] * x, row = float4-index / 25 (100 floats = 25 float4)
__global__ void scale_x(const float4* __restrict__ x4,
                        const float* __restrict__ dinv,
                        float4* __restrict__ xs4, int n25) {
    int i = blockIdx.x * blockDim.x + threadIdx.x;
    if (i < n25) {
        float d = dinv[i / 25];
        float4 v = x4[i];
        v.x *= d; v.y *= d; v.z *= d; v.w *= d;
        xs4[i] = v;
    }
}

// ---------------- pull-gather aggregation (pre-scaled tables) --------------

// agg[v][:] = dinv[v] * sum_{s in in(v) ∪ {v}} xs[s][:]
// One wave/node. Row = 25 float4. Lanes 0-24 even edges, 32-56 odd edges.
__global__ __launch_bounds__(256) void pull_f100(
        const float* __restrict__ xs, const int* __restrict__ rowptr,
        const int* __restrict__ csr, const float* __restrict__ dinv,
        float* __restrict__ agg, int n) {
    int wave = threadIdx.x >> 6, lane = threadIdx.x & 63;
    int v = blockIdx.x * 4 + wave;
    if (v >= n) return;
    int beg = rowptr[v], end = rowptr[v + 1];
    float dv = dinv[v];
    int half = lane >> 5, q = lane & 31;
    bool act = q < 25;
    float4 acc = {0.f, 0.f, 0.f, 0.f};
    if (half == 0 && act) acc = ((const float4*)(xs + (size_t)v * F0))[q];  // self

    for (int base = beg; base < end; base += 64) {
        int cnt = min(64, end - base);
        int sidx = (lane < cnt) ? csr[base + lane] : 0;
        int npf = cnt >> 1;
        int p = 0;
        for (; p + 4 <= npf; p += 4) {
            int s0 = __shfl(sidx, 2 * p + half, 64);
            int s1 = __shfl(sidx, 2 * p + 2 + half, 64);
            int s2 = __shfl(sidx, 2 * p + 4 + half, 64);
            int s3 = __shfl(sidx, 2 * p + 6 + half, 64);
            if (act) {
                float4 r0 = ((const float4*)(xs + (size_t)s0 * F0))[q];
                float4 r1 = ((const float4*)(xs + (size_t)s1 * F0))[q];
                float4 r2 = ((const float4*)(xs + (size_t)s2 * F0))[q];
                float4 r3 = ((const float4*)(xs + (size_t)s3 * F0))[q];
                acc.x += (r0.x + r1.x) + (r2.x + r3.x);
                acc.y += (r0.y + r1.y) + (r2.y + r3.y);
                acc.z += (r0.z + r1.z) + (r2.z + r3.z);
                acc.w += (r0.w + r1.w) + (r2.w + r3.w);
            }
        }
        for (; p < npf; p++) {
            int s0 = __shfl(sidx, 2 * p + half, 64);
            if (act) {
                float4 r0 = ((const float4*)(xs + (size_t)s0 * F0))[q];
                acc.x += r0.x; acc.y += r0.y; acc.z += r0.z; acc.w += r0.w;
            }
        }
        if (cnt & 1) {
            int sl = __shfl(sidx, cnt - 1, 64);
            if (half == 0 && act) {
                float4 r = ((const float4*)(xs + (size_t)sl * F0))[q];
                acc.x += r.x; acc.y += r.y; acc.z += r.z; acc.w += r.w;
            }
        }
    }
    float ox = __shfl_down(acc.x, 32, 64);
    float oy = __shfl_down(acc.y, 32, 64);
    float oz = __shfl_down(acc.z, 32, 64);
    float ow = __shfl_down(acc.w, 32, 64);
    if (half == 0 && act) {
        float4 r;
        r.x = dv * (acc.x + ox);
        r.y = dv * (acc.y + oy);
        r.z = dv * (acc.z + oz);
        r.w = dv * (acc.w + ow);
        ((float4*)(agg + (size_t)v * F0))[q] = r;
    }
}

// Layer-2 fused aggregation, XCD-pinned feature chunks, 4 nodes per wave.
// h2c layout: [8][n][16] chunk-major, rows pre-scaled by dinv[row] (gemm2).
// chunk = blockIdx.x & 7 -> XCD (blockIdx % 8 round-robin): each XCD's L2
// only sees its own contiguous 3.2 MB chunk slice (fits 4 MB L2).
// Wave = 4 nodes x 16 lanes; per node: 4 edge-slots (g2) x 4 float4-lanes (q)
// -> 4 independent csr->gather chains in flight per node, one 64 B line per
// 4-lane quad. 2-level butterfly across edge-slots, then relu(dv*agg+b2)·Wfc
// partial dot, atomicAdd into bfc-prefilled out.
__global__ __launch_bounds__(256) void pull_c16_fused(
        const float* __restrict__ h2c, const int* __restrict__ rowptr,
        const int* __restrict__ csr, const float* __restrict__ dinv,
        const float* __restrict__ b2, const float* __restrict__ Wfc,
        float* __restrict__ out, int n) {
    int chunk = blockIdx.x & 7;
    int nb = blockIdx.x >> 3;
    int wave = threadIdx.x >> 6, lane = threadIdx.x & 63;
    int grp = lane >> 4;          // node slot within wave (0..3)
    int g2  = (lane >> 2) & 3;    // edge slot (0..3)
    int q   = lane & 3;           // float4 slot within 16-float chunk row
    int v = nb * 16 + wave * 4 + grp;
    const float* __restrict__ tab = h2c + (size_t)chunk * n * 16;

    int beg = 0, end = 0;
    float dv = 0.f;
    if (v < n) {
        beg = rowptr[v];
        end = rowptr[v + 1];
        dv = dinv[v];
    }

    float4 acc = {0.f, 0.f, 0.f, 0.f};
    if (v < n && g2 == 0) acc = ((const float4*)(tab + (size_t)v * 16))[q];  // self

    for (int base = beg; base < end; base += 16) {
#pragma unroll
        for (int sub = 0; sub < 4; ++sub) {
            int e = base + sub * 4 + g2;
            if (e < end) {
                // nontemporal: keep the csr stream from evicting the table
                int s = __builtin_nontemporal_load(csr + e);
                float4 r = ((const float4*)(tab + (size_t)s * 16))[q];
                acc.x += r.x; acc.y += r.y; acc.z += r.z; acc.w += r.w;
            }
        }
    }
    // reduce across the 4 edge slots (within each 16-lane group)
#pragma unroll
    for (int off = 4; off <= 8; off <<= 1) {
        acc.x += __shfl_xor(acc.x, off, 64);
        acc.y += __shfl_xor(acc.y, off, 64);
        acc.z += __shfl_xor(acc.z, off, 64);
        acc.w += __shfl_xor(acc.w, off, 64);
    }
    int c0 = chunk * 16 + 4 * q;
    float4 bb = *(const float4*)(b2 + c0);
    float4 ww = *(const float4*)(Wfc + c0);
    float part = fmaxf(fmaf(dv, acc.x, bb.x), 0.f) * ww.x
               + fmaxf(fmaf(dv, acc.y, bb.y), 0.f) * ww.y
               + fmaxf(fmaf(dv, acc.z, bb.z), 0.f) * ww.z
               + fmaxf(fmaf(dv, acc.w, bb.w), 0.f) * ww.w;
    part += __shfl_xor(part, 1, 64);
    part += __shfl_xor(part, 2, 64);
    if (v < n && (lane & 15) == 0) atomicAdd(out + v, part);
}

// ---------------- dense transforms (fp32, 128x128 tile, 8x8 micro) --------
// Direct LDS staging (NO register prefetch — round-9 occupancy cliff).

// C = relu(A @ W + bias), A:[n,100], W:[100,256]. K chunked by 20.
__global__ __launch_bounds__(256) void gemm1_tiled(
        const float* __restrict__ A, const float* __restrict__ W,
        const float* __restrict__ bias, float* __restrict__ C, int n) {
    __shared__ float As[20 * 128];
    __shared__ float Bs[20 * 128];
    int tid = threadIdx.x;
    int r0 = blockIdx.x * 128;
    int c0 = blockIdx.y * 128;
    int tc = tid & 15, tr = tid >> 4;
    float acc[8][8] = {};

    for (int k0 = 0; k0 < F0; k0 += 20) {
        if (k0) __syncthreads();
        for (int idx = tid; idx < 128 * 5; idx += 256) {
            int row = idx & 127, kq = idx >> 7;
            int gr = r0 + row;
            if (gr >= n) gr = n - 1;
            float4 v = *(const float4*)(A + (size_t)gr * F0 + k0 + 4 * kq);
            As[(4 * kq + 0) * 128 + row] = v.x;
            As[(4 * kq + 1) * 128 + row] = v.y;
            As[(4 * kq + 2) * 128 + row] = v.z;
            As[(4 * kq + 3) * 128 + row] = v.w;
        }
        for (int idx = tid; idx < 20 * 32; idx += 256) {
            int k = idx >> 5, cq = idx & 31;
            *(float4*)(Bs + k * 128 + 4 * cq) =
                *(const float4*)(W + (size_t)(k0 + k) * F1 + c0 + 4 * cq);
        }
        __syncthreads();
#pragma unroll 5
        for (int k = 0; k < 20; k++) {
            float4 a0 = *(const float4*)(As + k * 128 + 4 * tr);
            float4 a1 = *(const float4*)(As + k * 128 + 64 + 4 * tr);
            float4 b0 = *(const float4*)(Bs + k * 128 + 4 * tc);
            float4 b1 = *(const float4*)(Bs + k * 128 + 64 + 4 * tc);
            float av[8] = {a0.x, a0.y, a0.z, a0.w, a1.x, a1.y, a1.z, a1.w};
            float bv[8] = {b0.x, b0.y, b0.z, b0.w, b1.x, b1.y, b1.z, b1.w};
#pragma unroll
            for (int i = 0; i < 8; i++)
#pragma unroll
                for (int j = 0; j < 8; j++) acc[i][j] += av[i] * bv[j];
        }
    }
    float4 bb0 = *(const float4*)(bias + c0 + 4 * tc);
    float4 bb1 = *(const float4*)(bias + c0 + 64 + 4 * tc);
    float bv[8] = {bb0.x, bb0.y, bb0.z, bb0.w, bb1.x, bb1.y, bb1.z, bb1.w};
#pragma unroll
    for (int i = 0; i < 8; i++) {
        int row = (i < 4) ? (4 * tr + i) : (64 + 4 * tr + i - 4);
        int gr = r0 + row;
        if (gr < n) {
            float4 o0, o1;
            o0.x = fmaxf(acc[i][0] + bv[0], 0.f);
            o0.y = fmaxf(acc[i][1] + bv[1], 0.f);
            o0.z = fmaxf(acc[i][2] + bv[2], 0.f);
            o0.w = fmaxf(acc[i][3] + bv[3], 0.f);
            o1.x = fmaxf(acc[i][4] + bv[4], 0.f);
            o1.y = fmaxf(acc[i][5] + bv[5], 0.f);
            o1.z = fmaxf(acc[i][6] + bv[6], 0.f);
            o1.w = fmaxf(acc[i][7] + bv[7], 0.f);
            *(float4*)(C + (size_t)gr * F1 + c0 + 4 * tc) = o0;
            *(float4*)(C + (size_t)gr * F1 + c0 + 64 + 4 * tc) = o1;
        }
    }
}

// h2c = dinv[row] * (A @ W), A:[n,256], W:[256,128]. 128 rows x full F2, K by 32.
// Epilogue stores CHUNK-MAJOR: h2c[(col>>4)][row][col&15], 64 B per 4 lanes.
__global__ __launch_bounds__(256) void gemm2_tiled(
        const float* __restrict__ A, const float* __restrict__ W,
        const float* __restrict__ dinv, float* __restrict__ C, int n) {
    __shared__ float As[32 * 128];
    __shared__ float Bs[32 * 128];
    int tid = threadIdx.x;
    int r0 = blockIdx.x * 128;
    int tc = tid & 15, tr = tid >> 4;
    float acc[8][8] = {};

    for (int k0 = 0; k0 < F1; k0 += 32) {
        if (k0) __syncthreads();
        for (int idx = tid; idx < 128 * 8; idx += 256) {
            int row = idx & 127, kq = idx >> 7;
            int gr = r0 + row;
            if (gr >= n) gr = n - 1;
            float4 v = *(const float4*)(A + (size_t)gr * F1 + k0 + 4 * kq);
            As[(4 * kq + 0) * 128 + row] = v.x;
            As[(4 * kq + 1) * 128 + row] = v.y;
            As[(4 * kq + 2) * 128 + row] = v.z;
            As[(4 * kq + 3) * 128 + row] = v.w;
        }
        for (int idx = tid; idx < 32 * 32; idx += 256) {
            int k = idx >> 5, cq = idx & 31;
            *(float4*)(Bs + k * 128 + 4 * cq) =
                *(const float4*)(W + (size_t)(k0 + k) * F2 + 4 * cq);
        }
        __syncthreads();
#pragma unroll 4
        for (int k = 0; k < 32; k++) {
            float4 a0 = *(const float4*)(As + k * 128 + 4 * tr);
            float4 a1 = *(const float4*)(As + k * 128 + 64 + 4 * tr);
            float4 b0 = *(const float4*)(Bs + k * 128 + 4 * tc);
            float4 b1 = *(const float4*)(Bs + k * 128 + 64 + 4 * tc);
            float av[8] = {a0.x, a0.y, a0.z, a0.w, a1.x, a1.y, a1.z, a1.w};
            float bv[8] = {b0.x, b0.y, b0.z, b0.w, b1.x, b1.y, b1.z, b1.w};
#pragma unroll
            for (int i = 0; i < 8; i++)
#pragma unroll
                for (int j = 0; j < 8; j++) acc[i][j] += av[i] * bv[j];
        }
    }
    int ch = tc >> 2;             // chunk of columns 4*tc (0..3)
    int of = (tc & 3) << 2;       // float4 offset inside 16-float chunk row
#pragma unroll
    for (int i = 0; i < 8; i++) {
        int row = (i < 4) ? (4 * tr + i) : (64 + 4 * tr + i - 4);
        int gr = r0 + row;
        if (gr < n) {
            float d = dinv[gr];
            float4 o0 = {acc[i][0] * d, acc[i][1] * d, acc[i][2] * d, acc[i][3] * d};
            float4 o1 = {acc[i][4] * d, acc[i][5] * d, acc[i][6] * d, acc[i][7] * d};
            *(float4*)(C + ((size_t)ch * n + gr) * 16 + of) = o0;        // cols 4tc..
            *(float4*)(C + ((size_t)(ch + 4) * n + gr) * 16 + of) = o1;  // cols 64+4tc..
        }
    }
}

// ---------------- launch ----------------

static inline size_t align16(size_t x) { return (x + 3) & ~(size_t)3; }  // in 4B elems

extern "C" void kernel_launch(void* const* d_in, const int* in_sizes, int n_in,
                              void* d_out, int out_size, void* d_ws, size_t ws_size,
                              hipStream_t stream) {
    const float* x   = (const float*)d_in[0];
    const int*   ei  = (const int*)d_in[1];
    const float* W1  = (const float*)d_in[2];
    const float* b1  = (const float*)d_in[3];
    const float* W2  = (const float*)d_in[4];
    const float* b2  = (const float*)d_in[5];
    const float* Wfc = (const float*)d_in[6];
    const float* bfc = (const float*)d_in[7];
    float* out = (float*)d_out;

    const int n = in_sizes[0] / F0;   // 50000
    const int e = in_sizes[1] / 2;    // 800000
    const int* src = ei;
    const int* dst = ei + e;

    // workspace layout (4-byte elements, each region 16B-aligned)
    char* wsb = (char*)d_ws;
    size_t off = 0;
    int* deg    = (int*)(wsb + 4 * off); off = align16(off + n);
    int* excl   = (int*)(wsb + 4 * off); off = align16(off + n);
    int* bsum   = (int*)(wsb + 4 * off); off = align16(off + 256);
    int* rowptr = (int*)(wsb + 4 * off); off = align16(off + n + 1);
    int* cursor = (int*)(wsb + 4 * off); off = align16(off + n);
    int* csr    = (int*)(wsb + 4 * off); off = align16(off + e);
    float* dinv = (float*)(wsb + 4 * off); off = align16(off + n);
    float* xs   = (float*)(wsb + 4 * off); off = align16(off + (size_t)n * F0);
    float* aggX = (float*)(wsb + 4 * off); off = align16(off + (size_t)n * F0);
    float* a1   = (float*)(wsb + 4 * off); off = align16(off + (size_t)n * F1);
    float* h2c  = (float*)(wsb + 4 * off); off = align16(off + (size_t)n * F2);

    const int B = 256;
    const int nb = (n + B - 1) / B;        // 196 (<= 256)
    const int rblocks = (n + 127) / 128;

    // CSR build + scaled-x table; prefill out with bfc for chunked atomics
    zero_i32<<<nb, B, 0, stream>>>(deg, n);
    fill_f32<<<nb, B, 0, stream>>>(out, bfc, n);
    deg_count_i<<<(e + B - 1) / B, B, 0, stream>>>(dst, deg, e);
    scan1<<<nb, B, 0, stream>>>(deg, excl, bsum, dinv, n);
    scale_x<<<((n * 25) + B - 1) / B, B, 0, stream>>>(
        (const float4*)x, dinv, (float4*)xs, n * 25);
    scan2<<<1, B, 0, stream>>>(bsum, nb, rowptr, n);
    scan3<<<nb, B, 0, stream>>>(excl, bsum, rowptr, cursor, n);
    csr_fill<<<(e + B - 1) / B, B, 0, stream>>>(src, dst, cursor, csr, e);

    // layer 1: pull-aggregate xs, then tiled GEMM + bias + relu
    pull_f100<<<(n + 3) / 4, 256, 0, stream>>>(xs, rowptr, csr, dinv, aggX, n);
    gemm1_tiled<<<dim3(rblocks, F1 / 128), 256, 0, stream>>>(aggX, W1, b1, a1, n);

    // layer 2: tiled GEMM -> chunk-major pre-scaled h2c, then XCD-pinned
    // chunked pull (4 nodes/wave) + bias + relu + FC (atomic partial dots)
    gemm2_tiled<<<rblocks, 256, 0, stream>>>(a1, W2, dinv, h2c, n);
    pull_c16_fused<<<8 * ((n + 15) / 16), 256, 0, stream>>>(
        h2c, rowptr, csr, dinv, b2, Wfc, out, n);
}

// Round 3
// 392.602 us; speedup vs baseline: 1.1847x; 1.0512x over previous
//
#include <hip/hip_runtime.h>
#include <hip/hip_bf16.h>

// GCN: out = relu(gcnconv(relu(gcnconv(x,W1,b1)), W2, b2)) @ Wfc + bfc
// N=50000, E=800000, F0=100, F1=256, F2=128. All-fp32 value path (bf16 blows
// the ~6e-6 relative threshold — round-4 post-mortem).
// Round 13: keep XCD-pinned chunk-major h2c ([8][n][16], chunk=blockIdx%8 ->
// 3.2 MB slice resident in that XCD's L2; FETCH 228->30 MB confirmed r11/r12).
// Fix the remaining latency bound (r12: 84 us, ~1 line outstanding/wave —
// the nontemporal csr load missed to HBM (~900 cy) at the head of every
// gather chain): block-cooperative LDS staging of the block's contiguous
// csr window (64 nodes ~ 1024 edges, one coalesced burst), plus staged
// rowptr/dinv. Gather loop now chains ds_read(120cy)->L2 gather(200cy),
// 4-deep per lane, 4 nodes per 16-lane group.

#define F0 100
#define F1 256
#define F2 128
#define CAP 2048   // staged csr window (ints); 64-node blocks avg ~1024 edges

// ---------------- CSR construction ----------------

__global__ void zero_i32(int* p, int n) {
    int i = blockIdx.x * blockDim.x + threadIdx.x;
    if (i < n) p[i] = 0;
}

// out[i] = bfc (pre-fill so chunk passes can atomicAdd without ordering)
__global__ void fill_f32(float* out, const float* __restrict__ bfc, int n) {
    int i = blockIdx.x * blockDim.x + threadIdx.x;
    if (i < n) out[i] = bfc[0];
}

__global__ void deg_count_i(const int* __restrict__ dst, int* deg, int e) {
    int i = blockIdx.x * blockDim.x + threadIdx.x;
    if (i < e) atomicAdd(deg + dst[i], 1);
}

// per-block exclusive scan of deg + block sums; also emits dinv = rsqrt(deg+1)
__global__ __launch_bounds__(256) void scan1(const int* __restrict__ deg,
                                             int* __restrict__ excl,
                                             int* __restrict__ bsum,
                                             float* __restrict__ dinv, int n) {
    __shared__ int wsum[4];
    int i = blockIdx.x * 256 + threadIdx.x;
    int lane = threadIdx.x & 63, wid = threadIdx.x >> 6;
    int v = (i < n) ? deg[i] : 0;
    if (i < n) dinv[i] = rsqrtf((float)(v + 1));
    int s = v;
#pragma unroll
    for (int off = 1; off < 64; off <<= 1) {
        int t = __shfl_up(s, off, 64);
        if (lane >= off) s += t;
    }
    if (lane == 63) wsum[wid] = s;
    __syncthreads();
    int add = 0;
    for (int w = 0; w < wid; w++) add += wsum[w];
    if (i < n) excl[i] = add + s - v;
    if (threadIdx.x == 255) bsum[blockIdx.x] = add + s;
}

__global__ __launch_bounds__(256) void scan2(int* __restrict__ bsum, int nb,
                                             int* __restrict__ rowptr, int n) {
    __shared__ int wsum[4];
    int lane = threadIdx.x & 63, wid = threadIdx.x >> 6;
    int v = (threadIdx.x < nb) ? bsum[threadIdx.x] : 0;
    int s = v;
#pragma unroll
    for (int off = 1; off < 64; off <<= 1) {
        int t = __shfl_up(s, off, 64);
        if (lane >= off) s += t;
    }
    if (lane == 63) wsum[wid] = s;
    __syncthreads();
    int add = 0;
    for (int w = 0; w < wid; w++) add += wsum[w];
    if (threadIdx.x < nb) bsum[threadIdx.x] = add + s - v;
    if (threadIdx.x == 255) rowptr[n] = add + s;
}

__global__ void scan3(const int* __restrict__ excl, const int* __restrict__ bsum,
                      int* __restrict__ rowptr, int* __restrict__ cursor, int n) {
    int i = blockIdx.x * 256 + threadIdx.x;
    if (i < n) {
        int r = excl[i] + bsum[blockIdx.x];
        rowptr[i] = r;
        cursor[i] = r;
    }
}

__global__ void csr_fill(const int* __restrict__ src, const int* __restrict__ dst,
                         int* cursor, int* __restrict__ csr, int e) {
    int i = blockIdx.x * blockDim.x + threadIdx.x;
    if (i < e) {
        int pos = atomicAdd(cursor + dst[i], 1);
        csr[pos] = src[i];
    }
}

// xs = dinv[row] * x, row = float4-index / 25 (100 floats = 25 float4)
__global__ void scale_x(const float4* __restrict__ x4,
                        const float* __restrict__ dinv,
                        float4* __restrict__ xs4, int n25) {
    int i = blockIdx.x * blockDim.x + threadIdx.x;
    if (i < n25) {
        float d = dinv[i / 25];
        float4 v = x4[i];
        v.x *= d; v.y *= d; v.z *= d; v.w *= d;
        xs4[i] = v;
    }
}

// ---------------- pull-gather aggregation (pre-scaled tables) --------------

// agg[v][:] = dinv[v] * sum_{s in in(v) ∪ {v}} xs[s][:]
// One wave/node. Row = 25 float4. Lanes 0-24 even edges, 32-56 odd edges.
__global__ __launch_bounds__(256) void pull_f100(
        const float* __restrict__ xs, const int* __restrict__ rowptr,
        const int* __restrict__ csr, const float* __restrict__ dinv,
        float* __restrict__ agg, int n) {
    int wave = threadIdx.x >> 6, lane = threadIdx.x & 63;
    int v = blockIdx.x * 4 + wave;
    if (v >= n) return;
    int beg = rowptr[v], end = rowptr[v + 1];
    float dv = dinv[v];
    int half = lane >> 5, q = lane & 31;
    bool act = q < 25;
    float4 acc = {0.f, 0.f, 0.f, 0.f};
    if (half == 0 && act) acc = ((const float4*)(xs + (size_t)v * F0))[q];  // self

    for (int base = beg; base < end; base += 64) {
        int cnt = min(64, end - base);
        int sidx = (lane < cnt) ? csr[base + lane] : 0;
        int npf = cnt >> 1;
        int p = 0;
        for (; p + 4 <= npf; p += 4) {
            int s0 = __shfl(sidx, 2 * p + half, 64);
            int s1 = __shfl(sidx, 2 * p + 2 + half, 64);
            int s2 = __shfl(sidx, 2 * p + 4 + half, 64);
            int s3 = __shfl(sidx, 2 * p + 6 + half, 64);
            if (act) {
                float4 r0 = ((const float4*)(xs + (size_t)s0 * F0))[q];
                float4 r1 = ((const float4*)(xs + (size_t)s1 * F0))[q];
                float4 r2 = ((const float4*)(xs + (size_t)s2 * F0))[q];
                float4 r3 = ((const float4*)(xs + (size_t)s3 * F0))[q];
                acc.x += (r0.x + r1.x) + (r2.x + r3.x);
                acc.y += (r0.y + r1.y) + (r2.y + r3.y);
                acc.z += (r0.z + r1.z) + (r2.z + r3.z);
                acc.w += (r0.w + r1.w) + (r2.w + r3.w);
            }
        }
        for (; p < npf; p++) {
            int s0 = __shfl(sidx, 2 * p + half, 64);
            if (act) {
                float4 r0 = ((const float4*)(xs + (size_t)s0 * F0))[q];
                acc.x += r0.x; acc.y += r0.y; acc.z += r0.z; acc.w += r0.w;
            }
        }
        if (cnt & 1) {
            int sl = __shfl(sidx, cnt - 1, 64);
            if (half == 0 && act) {
                float4 r = ((const float4*)(xs + (size_t)sl * F0))[q];
                acc.x += r.x; acc.y += r.y; acc.z += r.z; acc.w += r.w;
            }
        }
    }
    float ox = __shfl_down(acc.x, 32, 64);
    float oy = __shfl_down(acc.y, 32, 64);
    float oz = __shfl_down(acc.z, 32, 64);
    float ow = __shfl_down(acc.w, 32, 64);
    if (half == 0 && act) {
        float4 r;
        r.x = dv * (acc.x + ox);
        r.y = dv * (acc.y + oy);
        r.z = dv * (acc.z + oz);
        r.w = dv * (acc.w + ow);
        ((float4*)(agg + (size_t)v * F0))[q] = r;
    }
}

// Layer-2 fused aggregation, XCD-pinned feature chunks, LDS-staged csr.
// h2c layout: [8][n][16] chunk-major, rows pre-scaled by dinv[row] (gemm2).
// chunk = blockIdx.x & 7 -> XCD (blockIdx % 8 round-robin): each XCD's L2
// only sees its own 3.2 MB chunk slice. Block = 64 consecutive nodes; the
// block's contiguous csr window is staged to LDS in one coalesced
// nontemporal burst (HBM latency paid once per block, not per gather chain).
// Each 16-lane group: 4 nodes x 4 edge-slots (g2) x 4 float4-lanes (q);
// gather loop chains ds_read -> L2 gather, unroll 4 -> 4 lines in flight.
__global__ __launch_bounds__(256) void pull_c16_fused(
        const float* __restrict__ h2c, const int* __restrict__ rowptr,
        const int* __restrict__ csr, const float* __restrict__ dinv,
        const float* __restrict__ b2, const float* __restrict__ Wfc,
        float* __restrict__ out, int n) {
    __shared__ int s_row[65];
    __shared__ float s_dinv[64];
    __shared__ int s_csr[CAP];
    int chunk = blockIdx.x & 7;
    int nb = blockIdx.x >> 3;
    int v0 = nb * 64;
    int tid = threadIdx.x;
    int lane = tid & 63, wv = tid >> 6;
    int q = lane & 3;             // float4 slot within 16-float chunk row
    int g2 = (lane >> 2) & 3;     // edge slot (0..3)
    int grp = lane >> 4;          // 16-lane group within wave (0..3)
    const float* __restrict__ tab = h2c + (size_t)chunk * n * 16;

    if (tid <= 64) s_row[tid] = rowptr[min(v0 + tid, n)];
    if (tid < 64) s_dinv[tid] = (v0 + tid < n) ? dinv[v0 + tid] : 0.f;
    __syncthreads();
    int ebeg = s_row[0], eend = s_row[64];

    int base_local = wv * 16 + grp * 4;   // first of this group's 4 nodes

    float4 acc[4];
#pragma unroll
    for (int nn = 0; nn < 4; ++nn) acc[nn] = (float4){0.f, 0.f, 0.f, 0.f};

    // self term
#pragma unroll
    for (int nn = 0; nn < 4; ++nn) {
        int node = v0 + base_local + nn;
        if (node < n && g2 == 0)
            acc[nn] = ((const float4*)(tab + (size_t)node * 16))[q];
    }

    for (int w0 = ebeg; w0 < eend; w0 += CAP) {
        int wcnt = min(CAP, eend - w0);
        if (w0 != ebeg) __syncthreads();
        for (int i = tid; i < wcnt; i += 256)
            s_csr[i] = __builtin_nontemporal_load(csr + w0 + i);
        __syncthreads();
#pragma unroll
        for (int nn = 0; nn < 4; ++nn) {
            int local = base_local + nn;
            int nbg = max(s_row[local], w0);
            int nen = min(s_row[local + 1], w0 + wcnt);
#pragma unroll 4
            for (int e = nbg + g2; e < nen; e += 4) {
                int s = s_csr[e - w0];
                float4 r = ((const float4*)(tab + (size_t)s * 16))[q];
                acc[nn].x += r.x; acc[nn].y += r.y;
                acc[nn].z += r.z; acc[nn].w += r.w;
            }
        }
    }

    int c0 = chunk * 16 + 4 * q;
    float4 bb = *(const float4*)(b2 + c0);
    float4 ww = *(const float4*)(Wfc + c0);
#pragma unroll
    for (int nn = 0; nn < 4; ++nn) {
        int local = base_local + nn;
        int node = v0 + local;
        float dv = s_dinv[local];
        float4 a = acc[nn];
        // reduce across the 4 edge slots (within each 16-lane group)
        a.x += __shfl_xor(a.x, 4, 64);
        a.y += __shfl_xor(a.y, 4, 64);
        a.z += __shfl_xor(a.z, 4, 64);
        a.w += __shfl_xor(a.w, 4, 64);
        a.x += __shfl_xor(a.x, 8, 64);
        a.y += __shfl_xor(a.y, 8, 64);
        a.z += __shfl_xor(a.z, 8, 64);
        a.w += __shfl_xor(a.w, 8, 64);
        float part = fmaxf(fmaf(dv, a.x, bb.x), 0.f) * ww.x
                   + fmaxf(fmaf(dv, a.y, bb.y), 0.f) * ww.y
                   + fmaxf(fmaf(dv, a.z, bb.z), 0.f) * ww.z
                   + fmaxf(fmaf(dv, a.w, bb.w), 0.f) * ww.w;
        part += __shfl_xor(part, 1, 64);
        part += __shfl_xor(part, 2, 64);
        if (node < n && (lane & 15) == 0) atomicAdd(out + node, part);
    }
}

// ---------------- dense transforms (fp32, 128x128 tile, 8x8 micro) --------
// Direct LDS staging (NO register prefetch — round-9 occupancy cliff).

// C = relu(A @ W + bias), A:[n,100], W:[100,256]. K chunked by 20.
__global__ __launch_bounds__(256) void gemm1_tiled(
        const float* __restrict__ A, const float* __restrict__ W,
        const float* __restrict__ bias, float* __restrict__ C, int n) {
    __shared__ float As[20 * 128];
    __shared__ float Bs[20 * 128];
    int tid = threadIdx.x;
    int r0 = blockIdx.x * 128;
    int c0 = blockIdx.y * 128;
    int tc = tid & 15, tr = tid >> 4;
    float acc[8][8] = {};

    for (int k0 = 0; k0 < F0; k0 += 20) {
        if (k0) __syncthreads();
        for (int idx = tid; idx < 128 * 5; idx += 256) {
            int row = idx & 127, kq = idx >> 7;
            int gr = r0 + row;
            if (gr >= n) gr = n - 1;
            float4 v = *(const float4*)(A + (size_t)gr * F0 + k0 + 4 * kq);
            As[(4 * kq + 0) * 128 + row] = v.x;
            As[(4 * kq + 1) * 128 + row] = v.y;
            As[(4 * kq + 2) * 128 + row] = v.z;
            As[(4 * kq + 3) * 128 + row] = v.w;
        }
        for (int idx = tid; idx < 20 * 32; idx += 256) {
            int k = idx >> 5, cq = idx & 31;
            *(float4*)(Bs + k * 128 + 4 * cq) =
                *(const float4*)(W + (size_t)(k0 + k) * F1 + c0 + 4 * cq);
        }
        __syncthreads();
#pragma unroll 5
        for (int k = 0; k < 20; k++) {
            float4 a0 = *(const float4*)(As + k * 128 + 4 * tr);
            float4 a1 = *(const float4*)(As + k * 128 + 64 + 4 * tr);
            float4 b0 = *(const float4*)(Bs + k * 128 + 4 * tc);
            float4 b1 = *(const float4*)(Bs + k * 128 + 64 + 4 * tc);
            float av[8] = {a0.x, a0.y, a0.z, a0.w, a1.x, a1.y, a1.z, a1.w};
            float bv[8] = {b0.x, b0.y, b0.z, b0.w, b1.x, b1.y, b1.z, b1.w};
#pragma unroll
            for (int i = 0; i < 8; i++)
#pragma unroll
                for (int j = 0; j < 8; j++) acc[i][j] += av[i] * bv[j];
        }
    }
    float4 bb0 = *(const float4*)(bias + c0 + 4 * tc);
    float4 bb1 = *(const float4*)(bias + c0 + 64 + 4 * tc);
    float bv[8] = {bb0.x, bb0.y, bb0.z, bb0.w, bb1.x, bb1.y, bb1.z, bb1.w};
#pragma unroll
    for (int i = 0; i < 8; i++) {
        int row = (i < 4) ? (4 * tr + i) : (64 + 4 * tr + i - 4);
        int gr = r0 + row;
        if (gr < n) {
            float4 o0, o1;
            o0.x = fmaxf(acc[i][0] + bv[0], 0.f);
            o0.y = fmaxf(acc[i][1] + bv[1], 0.f);
            o0.z = fmaxf(acc[i][2] + bv[2], 0.f);
            o0.w = fmaxf(acc[i][3] + bv[3], 0.f);
            o1.x = fmaxf(acc[i][4] + bv[4], 0.f);
            o1.y = fmaxf(acc[i][5] + bv[5], 0.f);
            o1.z = fmaxf(acc[i][6] + bv[6], 0.f);
            o1.w = fmaxf(acc[i][7] + bv[7], 0.f);
            *(float4*)(C + (size_t)gr * F1 + c0 + 4 * tc) = o0;
            *(float4*)(C + (size_t)gr * F1 + c0 + 64 + 4 * tc) = o1;
        }
    }
}

// h2c = dinv[row] * (A @ W), A:[n,256], W:[256,128]. 128 rows x full F2, K by 32.
// Epilogue stores CHUNK-MAJOR: h2c[(col>>4)][row][col&15], 64 B per 4 lanes.
__global__ __launch_bounds__(256) void gemm2_tiled(
        const float* __restrict__ A, const float* __restrict__ W,
        const float* __restrict__ dinv, float* __restrict__ C, int n) {
    __shared__ float As[32 * 128];
    __shared__ float Bs[32 * 128];
    int tid = threadIdx.x;
    int r0 = blockIdx.x * 128;
    int tc = tid & 15, tr = tid >> 4;
    float acc[8][8] = {};

    for (int k0 = 0; k0 < F1; k0 += 32) {
        if (k0) __syncthreads();
        for (int idx = tid; idx < 128 * 8; idx += 256) {
            int row = idx & 127, kq = idx >> 7;
            int gr = r0 + row;
            if (gr >= n) gr = n - 1;
            float4 v = *(const float4*)(A + (size_t)gr * F1 + k0 + 4 * kq);
            As[(4 * kq + 0) * 128 + row] = v.x;
            As[(4 * kq + 1) * 128 + row] = v.y;
            As[(4 * kq + 2) * 128 + row] = v.z;
            As[(4 * kq + 3) * 128 + row] = v.w;
        }
        for (int idx = tid; idx < 32 * 32; idx += 256) {
            int k = idx >> 5, cq = idx & 31;
            *(float4*)(Bs + k * 128 + 4 * cq) =
                *(const float4*)(W + (size_t)(k0 + k) * F2 + 4 * cq);
        }
        __syncthreads();
#pragma unroll 4
        for (int k = 0; k < 32; k++) {
            float4 a0 = *(const float4*)(As + k * 128 + 4 * tr);
            float4 a1 = *(const float4*)(As + k * 128 + 64 + 4 * tr);
            float4 b0 = *(const float4*)(Bs + k * 128 + 4 * tc);
            float4 b1 = *(const float4*)(Bs + k * 128 + 64 + 4 * tc);
            float av[8] = {a0.x, a0.y, a0.z, a0.w, a1.x, a1.y, a1.z, a1.w};
            float bv[8] = {b0.x, b0.y, b0.z, b0.w, b1.x, b1.y, b1.z, b1.w};
#pragma unroll
            for (int i = 0; i < 8; i++)
#pragma unroll
                for (int j = 0; j < 8; j++) acc[i][j] += av[i] * bv[j];
        }
    }
    int ch = tc >> 2;             // chunk of columns 4*tc (0..3)
    int of = (tc & 3) << 2;       // float4 offset inside 16-float chunk row
#pragma unroll
    for (int i = 0; i < 8; i++) {
        int row = (i < 4) ? (4 * tr + i) : (64 + 4 * tr + i - 4);
        int gr = r0 + row;
        if (gr < n) {
            float d = dinv[gr];
            float4 o0 = {acc[i][0] * d, acc[i][1] * d, acc[i][2] * d, acc[i][3] * d};
            float4 o1 = {acc[i][4] * d, acc[i][5] * d, acc[i][6] * d, acc[i][7] * d};
            *(float4*)(C + ((size_t)ch * n + gr) * 16 + of) = o0;        // cols 4tc..
            *(float4*)(C + ((size_t)(ch + 4) * n + gr) * 16 + of) = o1;  // cols 64+4tc..
        }
    }
}

// ---------------- launch ----------------

static inline size_t align16(size_t x) { return (x + 3) & ~(size_t)3; }  // in 4B elems

extern "C" void kernel_launch(void* const* d_in, const int* in_sizes, int n_in,
                              void* d_out, int out_size, void* d_ws, size_t ws_size,
                              hipStream_t stream) {
    const float* x   = (const float*)d_in[0];
    const int*   ei  = (const int*)d_in[1];
    const float* W1  = (const float*)d_in[2];
    const float* b1  = (const float*)d_in[3];
    const float* W2  = (const float*)d_in[4];
    const float* b2  = (const float*)d_in[5];
    const float* Wfc = (const float*)d_in[6];
    const float* bfc = (const float*)d_in[7];
    float* out = (float*)d_out;

    const int n = in_sizes[0] / F0;   // 50000
    const int e = in_sizes[1] / 2;    // 800000
    const int* src = ei;
    const int* dst = ei + e;

    // workspace layout (4-byte elements, each region 16B-aligned)
    char* wsb = (char*)d_ws;
    size_t off = 0;
    int* deg    = (int*)(wsb + 4 * off); off = align16(off + n);
    int* excl   = (int*)(wsb + 4 * off); off = align16(off + n);
    int* bsum   = (int*)(wsb + 4 * off); off = align16(off + 256);
    int* rowptr = (int*)(wsb + 4 * off); off = align16(off + n + 1);
    int* cursor = (int*)(wsb + 4 * off); off = align16(off + n);
    int* csr    = (int*)(wsb + 4 * off); off = align16(off + e);
    float* dinv = (float*)(wsb + 4 * off); off = align16(off + n);
    float* xs   = (float*)(wsb + 4 * off); off = align16(off + (size_t)n * F0);
    float* aggX = (float*)(wsb + 4 * off); off = align16(off + (size_t)n * F0);
    float* a1   = (float*)(wsb + 4 * off); off = align16(off + (size_t)n * F1);
    float* h2c  = (float*)(wsb + 4 * off); off = align16(off + (size_t)n * F2);

    const int B = 256;
    const int nb = (n + B - 1) / B;        // 196 (<= 256)
    const int rblocks = (n + 127) / 128;

    // CSR build + scaled-x table; prefill out with bfc for chunked atomics
    zero_i32<<<nb, B, 0, stream>>>(deg, n);
    fill_f32<<<nb, B, 0, stream>>>(out, bfc, n);
    deg_count_i<<<(e + B - 1) / B, B, 0, stream>>>(dst, deg, e);
    scan1<<<nb, B, 0, stream>>>(deg, excl, bsum, dinv, n);
    scale_x<<<((n * 25) + B - 1) / B, B, 0, stream>>>(
        (const float4*)x, dinv, (float4*)xs, n * 25);
    scan2<<<1, B, 0, stream>>>(bsum, nb, rowptr, n);
    scan3<<<nb, B, 0, stream>>>(excl, bsum, rowptr, cursor, n);
    csr_fill<<<(e + B - 1) / B, B, 0, stream>>>(src, dst, cursor, csr, e);

    // layer 1: pull-aggregate xs, then tiled GEMM + bias + relu
    pull_f100<<<(n + 3) / 4, 256, 0, stream>>>(xs, rowptr, csr, dinv, aggX, n);
    gemm1_tiled<<<dim3(rblocks, F1 / 128), 256, 0, stream>>>(aggX, W1, b1, a1, n);

    // layer 2: tiled GEMM -> chunk-major pre-scaled h2c, then XCD-pinned
    // chunked pull (LDS-staged csr) + bias + relu + FC (atomic partial dots)
    gemm2_tiled<<<rblocks, 256, 0, stream>>>(a1, W2, dinv, h2c, n);
    pull_c16_fused<<<8 * ((n + 63) / 64), 256, 0, stream>>>(
        h2c, rowptr, csr, dinv, b2, Wfc, out, n);
}

// Round 4
// 389.527 us; speedup vs baseline: 1.1941x; 1.0079x over previous
//
#include <hip/hip_runtime.h>
#include <hip/hip_bf16.h>

// GCN: out = relu(gcnconv(relu(gcnconv(x,W1,b1)), W2, b2)) @ Wfc + bfc
// N=50000, E=800000, F0=100, F1=256, F2=128. All-fp32 value path (bf16 blows
// the ~6e-6 relative threshold — round-4 post-mortem).
// Round 14: keep XCD-pinned chunk-major h2c ([8][n][16], chunk=blockIdx%8,
// 3.2 MB slice resident per-XCD L2; FETCH 228->27 MB confirmed r11-r13) and
// LDS-staged csr windows (r13). Fix the serialized gather chain (r13: 300 cy
// per 4-edge iteration, no overlap — branchy unroll defeated the scheduler):
// slot g2 now owns 4 CONSECUTIVE edges; explicit straight-line batch of
// 4 clamped LDS index reads -> 4 gathers -> masked (cndmask) adds. 4 lines
// in flight per lane instead of 1.

#define F0 100
#define F1 256
#define F2 128
#define CAP 2048   // staged csr window (ints); 64-node blocks avg ~1024 edges

// ---------------- CSR construction ----------------

__global__ void zero_i32(int* p, int n) {
    int i = blockIdx.x * blockDim.x + threadIdx.x;
    if (i < n) p[i] = 0;
}

// out[i] = bfc (pre-fill so chunk passes can atomicAdd without ordering)
__global__ void fill_f32(float* out, const float* __restrict__ bfc, int n) {
    int i = blockIdx.x * blockDim.x + threadIdx.x;
    if (i < n) out[i] = bfc[0];
}

__global__ void deg_count_i(const int* __restrict__ dst, int* deg, int e) {
    int i = blockIdx.x * blockDim.x + threadIdx.x;
    if (i < e) atomicAdd(deg + dst[i], 1);
}

// per-block exclusive scan of deg + block sums; also emits dinv = rsqrt(deg+1)
__global__ __launch_bounds__(256) void scan1(const int* __restrict__ deg,
                                             int* __restrict__ excl,
                                             int* __restrict__ bsum,
                                             float* __restrict__ dinv, int n) {
    __shared__ int wsum[4];
    int i = blockIdx.x * 256 + threadIdx.x;
    int lane = threadIdx.x & 63, wid = threadIdx.x >> 6;
    int v = (i < n) ? deg[i] : 0;
    if (i < n) dinv[i] = rsqrtf((float)(v + 1));
    int s = v;
#pragma unroll
    for (int off = 1; off < 64; off <<= 1) {
        int t = __shfl_up(s, off, 64);
        if (lane >= off) s += t;
    }
    if (lane == 63) wsum[wid] = s;
    __syncthreads();
    int add = 0;
    for (int w = 0; w < wid; w++) add += wsum[w];
    if (i < n) excl[i] = add + s - v;
    if (threadIdx.x == 255) bsum[blockIdx.x] = add + s;
}

__global__ __launch_bounds__(256) void scan2(int* __restrict__ bsum, int nb,
                                             int* __restrict__ rowptr, int n) {
    __shared__ int wsum[4];
    int lane = threadIdx.x & 63, wid = threadIdx.x >> 6;
    int v = (threadIdx.x < nb) ? bsum[threadIdx.x] : 0;
    int s = v;
#pragma unroll
    for (int off = 1; off < 64; off <<= 1) {
        int t = __shfl_up(s, off, 64);
        if (lane >= off) s += t;
    }
    if (lane == 63) wsum[wid] = s;
    __syncthreads();
    int add = 0;
    for (int w = 0; w < wid; w++) add += wsum[w];
    if (threadIdx.x < nb) bsum[threadIdx.x] = add + s - v;
    if (threadIdx.x == 255) rowptr[n] = add + s;
}

__global__ void scan3(const int* __restrict__ excl, const int* __restrict__ bsum,
                      int* __restrict__ rowptr, int* __restrict__ cursor, int n) {
    int i = blockIdx.x * 256 + threadIdx.x;
    if (i < n) {
        int r = excl[i] + bsum[blockIdx.x];
        rowptr[i] = r;
        cursor[i] = r;
    }
}

__global__ void csr_fill(const int* __restrict__ src, const int* __restrict__ dst,
                         int* cursor, int* __restrict__ csr, int e) {
    int i = blockIdx.x * blockDim.x + threadIdx.x;
    if (i < e) {
        int pos = atomicAdd(cursor + dst[i], 1);
        csr[pos] = src[i];
    }
}

// xs = dinv[row] * x, row = float4-index / 25 (100 floats = 25 float4)
__global__ void scale_x(const float4* __restrict__ x4,
                        const float* __restrict__ dinv,
                        float4* __restrict__ xs4, int n25) {
    int i = blockIdx.x * blockDim.x + threadIdx.x;
    if (i < n25) {
        float d = dinv[i / 25];
        float4 v = x4[i];
        v.x *= d; v.y *= d; v.z *= d; v.w *= d;
        xs4[i] = v;
    }
}

// ---------------- pull-gather aggregation (pre-scaled tables) --------------

// agg[v][:] = dinv[v] * sum_{s in in(v) ∪ {v}} xs[s][:]
// One wave/node. Row = 25 float4. Lanes 0-24 even edges, 32-56 odd edges.
__global__ __launch_bounds__(256) void pull_f100(
        const float* __restrict__ xs, const int* __restrict__ rowptr,
        const int* __restrict__ csr, const float* __restrict__ dinv,
        float* __restrict__ agg, int n) {
    int wave = threadIdx.x >> 6, lane = threadIdx.x & 63;
    int v = blockIdx.x * 4 + wave;
    if (v >= n) return;
    int beg = rowptr[v], end = rowptr[v + 1];
    float dv = dinv[v];
    int half = lane >> 5, q = lane & 31;
    bool act = q < 25;
    float4 acc = {0.f, 0.f, 0.f, 0.f};
    if (half == 0 && act) acc = ((const float4*)(xs + (size_t)v * F0))[q];  // self

    for (int base = beg; base < end; base += 64) {
        int cnt = min(64, end - base);
        int sidx = (lane < cnt) ? csr[base + lane] : 0;
        int npf = cnt >> 1;
        int p = 0;
        for (; p + 4 <= npf; p += 4) {
            int s0 = __shfl(sidx, 2 * p + half, 64);
            int s1 = __shfl(sidx, 2 * p + 2 + half, 64);
            int s2 = __shfl(sidx, 2 * p + 4 + half, 64);
            int s3 = __shfl(sidx, 2 * p + 6 + half, 64);
            if (act) {
                float4 r0 = ((const float4*)(xs + (size_t)s0 * F0))[q];
                float4 r1 = ((const float4*)(xs + (size_t)s1 * F0))[q];
                float4 r2 = ((const float4*)(xs + (size_t)s2 * F0))[q];
                float4 r3 = ((const float4*)(xs + (size_t)s3 * F0))[q];
                acc.x += (r0.x + r1.x) + (r2.x + r3.x);
                acc.y += (r0.y + r1.y) + (r2.y + r3.y);
                acc.z += (r0.z + r1.z) + (r2.z + r3.z);
                acc.w += (r0.w + r1.w) + (r2.w + r3.w);
            }
        }
        for (; p < npf; p++) {
            int s0 = __shfl(sidx, 2 * p + half, 64);
            if (act) {
                float4 r0 = ((const float4*)(xs + (size_t)s0 * F0))[q];
                acc.x += r0.x; acc.y += r0.y; acc.z += r0.z; acc.w += r0.w;
            }
        }
        if (cnt & 1) {
            int sl = __shfl(sidx, cnt - 1, 64);
            if (half == 0 && act) {
                float4 r = ((const float4*)(xs + (size_t)sl * F0))[q];
                acc.x += r.x; acc.y += r.y; acc.z += r.z; acc.w += r.w;
            }
        }
    }
    float ox = __shfl_down(acc.x, 32, 64);
    float oy = __shfl_down(acc.y, 32, 64);
    float oz = __shfl_down(acc.z, 32, 64);
    float ow = __shfl_down(acc.w, 32, 64);
    if (half == 0 && act) {
        float4 r;
        r.x = dv * (acc.x + ox);
        r.y = dv * (acc.y + oy);
        r.z = dv * (acc.z + oz);
        r.w = dv * (acc.w + ow);
        ((float4*)(agg + (size_t)v * F0))[q] = r;
    }
}

// Layer-2 fused aggregation, XCD-pinned feature chunks, LDS-staged csr.
// h2c layout: [8][n][16] chunk-major, rows pre-scaled by dinv[row] (gemm2).
// chunk = blockIdx.x & 7 -> XCD; block = 64 consecutive nodes; csr window
// staged to LDS (one coalesced nontemporal burst). Each 16-lane group
// processes 4 nodes sequentially; slot g2 owns 4 CONSECUTIVE edges per trip
// (stride 16). Straight-line batch: 4 clamped LDS index reads -> 4 gathers
// -> cndmask'd adds => 4 lines in flight per lane (r13 had 1).
__global__ __launch_bounds__(256) void pull_c16_fused(
        const float* __restrict__ h2c, const int* __restrict__ rowptr,
        const int* __restrict__ csr, const float* __restrict__ dinv,
        const float* __restrict__ b2, const float* __restrict__ Wfc,
        float* __restrict__ out, int n) {
    __shared__ int s_row[65];
    __shared__ float s_dinv[64];
    __shared__ int s_csr[CAP];
    int chunk = blockIdx.x & 7;
    int nb = blockIdx.x >> 3;
    int v0 = nb * 64;
    int tid = threadIdx.x;
    int lane = tid & 63, wv = tid >> 6;
    int q = lane & 3;             // float4 slot within 16-float chunk row
    int g2 = (lane >> 2) & 3;     // edge slot (0..3)
    int grp = lane >> 4;          // 16-lane group within wave (0..3)
    const float* __restrict__ tab = h2c + (size_t)chunk * n * 16;

    if (tid <= 64) s_row[tid] = rowptr[min(v0 + tid, n)];
    if (tid < 64) s_dinv[tid] = (v0 + tid < n) ? dinv[v0 + tid] : 0.f;
    __syncthreads();
    int ebeg = s_row[0], eend = s_row[64];

    int base_local = wv * 16 + grp * 4;   // first of this group's 4 nodes

    float4 acc[4];
#pragma unroll
    for (int nn = 0; nn < 4; ++nn) acc[nn] = (float4){0.f, 0.f, 0.f, 0.f};

    // self term
#pragma unroll
    for (int nn = 0; nn < 4; ++nn) {
        int node = v0 + base_local + nn;
        if (node < n && g2 == 0)
            acc[nn] = ((const float4*)(tab + (size_t)node * 16))[q];
    }

    for (int w0 = ebeg; w0 < eend; w0 += CAP) {
        int wcnt = min(CAP, eend - w0);
        if (w0 != ebeg) __syncthreads();
        for (int i = tid; i < wcnt; i += 256)
            s_csr[i] = __builtin_nontemporal_load(csr + w0 + i);
        __syncthreads();
#pragma unroll
        for (int nn = 0; nn < 4; ++nn) {
            int local = base_local + nn;
            int nbg = max(s_row[local], w0) - w0;
            int nen = min(s_row[local + 1], w0 + wcnt) - w0;
            for (int t = nbg + 4 * g2; t < nen; t += 16) {
                // 4 consecutive edges, clamped (always-valid) -> branch-free
                int i1 = min(t + 1, nen - 1);
                int i2 = min(t + 2, nen - 1);
                int i3 = min(t + 3, nen - 1);
                int s0 = s_csr[t];
                int s1 = s_csr[i1];
                int s2 = s_csr[i2];
                int s3 = s_csr[i3];
                float4 r0 = ((const float4*)(tab + (size_t)s0 * 16))[q];
                float4 r1 = ((const float4*)(tab + (size_t)s1 * 16))[q];
                float4 r2 = ((const float4*)(tab + (size_t)s2 * 16))[q];
                float4 r3 = ((const float4*)(tab + (size_t)s3 * 16))[q];
                bool m1 = (t + 1 < nen), m2 = (t + 2 < nen), m3 = (t + 3 < nen);
                acc[nn].x += r0.x + (m1 ? r1.x : 0.f);
                acc[nn].y += r0.y + (m1 ? r1.y : 0.f);
                acc[nn].z += r0.z + (m1 ? r1.z : 0.f);
                acc[nn].w += r0.w + (m1 ? r1.w : 0.f);
                acc[nn].x += (m2 ? r2.x : 0.f) + (m3 ? r3.x : 0.f);
                acc[nn].y += (m2 ? r2.y : 0.f) + (m3 ? r3.y : 0.f);
                acc[nn].z += (m2 ? r2.z : 0.f) + (m3 ? r3.z : 0.f);
                acc[nn].w += (m2 ? r2.w : 0.f) + (m3 ? r3.w : 0.f);
            }
        }
    }

    int c0 = chunk * 16 + 4 * q;
    float4 bb = *(const float4*)(b2 + c0);
    float4 ww = *(const float4*)(Wfc + c0);
#pragma unroll
    for (int nn = 0; nn < 4; ++nn) {
        int local = base_local + nn;
        int node = v0 + local;
        float dv = s_dinv[local];
        float4 a = acc[nn];
        // reduce across the 4 edge slots (within each 16-lane group)
        a.x += __shfl_xor(a.x, 4, 64);
        a.y += __shfl_xor(a.y, 4, 64);
        a.z += __shfl_xor(a.z, 4, 64);
        a.w += __shfl_xor(a.w, 4, 64);
        a.x += __shfl_xor(a.x, 8, 64);
        a.y += __shfl_xor(a.y, 8, 64);
        a.z += __shfl_xor(a.z, 8, 64);
        a.w += __shfl_xor(a.w, 8, 64);
        float part = fmaxf(fmaf(dv, a.x, bb.x), 0.f) * ww.x
                   + fmaxf(fmaf(dv, a.y, bb.y), 0.f) * ww.y
                   + fmaxf(fmaf(dv, a.z, bb.z), 0.f) * ww.z
                   + fmaxf(fmaf(dv, a.w, bb.w), 0.f) * ww.w;
        part += __shfl_xor(part, 1, 64);
        part += __shfl_xor(part, 2, 64);
        if (node < n && (lane & 15) == 0) atomicAdd(out + node, part);
    }
}

// ---------------- dense transforms (fp32, 128x128 tile, 8x8 micro) --------
// Direct LDS staging (NO register prefetch — round-9 occupancy cliff).

// C = relu(A @ W + bias), A:[n,100], W:[100,256]. K chunked by 20.
__global__ __launch_bounds__(256) void gemm1_tiled(
        const float* __restrict__ A, const float* __restrict__ W,
        const float* __restrict__ bias, float* __restrict__ C, int n) {
    __shared__ float As[20 * 128];
    __shared__ float Bs[20 * 128];
    int tid = threadIdx.x;
    int r0 = blockIdx.x * 128;
    int c0 = blockIdx.y * 128;
    int tc = tid & 15, tr = tid >> 4;
    float acc[8][8] = {};

    for (int k0 = 0; k0 < F0; k0 += 20) {
        if (k0) __syncthreads();
        for (int idx = tid; idx < 128 * 5; idx += 256) {
            int row = idx & 127, kq = idx >> 7;
            int gr = r0 + row;
            if (gr >= n) gr = n - 1;
            float4 v = *(const float4*)(A + (size_t)gr * F0 + k0 + 4 * kq);
            As[(4 * kq + 0) * 128 + row] = v.x;
            As[(4 * kq + 1) * 128 + row] = v.y;
            As[(4 * kq + 2) * 128 + row] = v.z;
            As[(4 * kq + 3) * 128 + row] = v.w;
        }
        for (int idx = tid; idx < 20 * 32; idx += 256) {
            int k = idx >> 5, cq = idx & 31;
            *(float4*)(Bs + k * 128 + 4 * cq) =
                *(const float4*)(W + (size_t)(k0 + k) * F1 + c0 + 4 * cq);
        }
        __syncthreads();
#pragma unroll 5
        for (int k = 0; k < 20; k++) {
            float4 a0 = *(const float4*)(As + k * 128 + 4 * tr);
            float4 a1 = *(const float4*)(As + k * 128 + 64 + 4 * tr);
            float4 b0 = *(const float4*)(Bs + k * 128 + 4 * tc);
            float4 b1 = *(const float4*)(Bs + k * 128 + 64 + 4 * tc);
            float av[8] = {a0.x, a0.y, a0.z, a0.w, a1.x, a1.y, a1.z, a1.w};
            float bv[8] = {b0.x, b0.y, b0.z, b0.w, b1.x, b1.y, b1.z, b1.w};
#pragma unroll
            for (int i = 0; i < 8; i++)
#pragma unroll
                for (int j = 0; j < 8; j++) acc[i][j] += av[i] * bv[j];
        }
    }
    float4 bb0 = *(const float4*)(bias + c0 + 4 * tc);
    float4 bb1 = *(const float4*)(bias + c0 + 64 + 4 * tc);
    float bv[8] = {bb0.x, bb0.y, bb0.z, bb0.w, bb1.x, bb1.y, bb1.z, bb1.w};
#pragma unroll
    for (int i = 0; i < 8; i++) {
        int row = (i < 4) ? (4 * tr + i) : (64 + 4 * tr + i - 4);
        int gr = r0 + row;
        if (gr < n) {
            float4 o0, o1;
            o0.x = fmaxf(acc[i][0] + bv[0], 0.f);
            o0.y = fmaxf(acc[i][1] + bv[1], 0.f);
            o0.z = fmaxf(acc[i][2] + bv[2], 0.f);
            o0.w = fmaxf(acc[i][3] + bv[3], 0.f);
            o1.x = fmaxf(acc[i][4] + bv[4], 0.f);
            o1.y = fmaxf(acc[i][5] + bv[5], 0.f);
            o1.z = fmaxf(acc[i][6] + bv[6], 0.f);
            o1.w = fmaxf(acc[i][7] + bv[7], 0.f);
            *(float4*)(C + (size_t)gr * F1 + c0 + 4 * tc) = o0;
            *(float4*)(C + (size_t)gr * F1 + c0 + 64 + 4 * tc) = o1;
        }
    }
}

// h2c = dinv[row] * (A @ W), A:[n,256], W:[256,128]. 128 rows x full F2, K by 32.
// Epilogue stores CHUNK-MAJOR: h2c[(col>>4)][row][col&15], 64 B per 4 lanes.
__global__ __launch_bounds__(256) void gemm2_tiled(
        const float* __restrict__ A, const float* __restrict__ W,
        const float* __restrict__ dinv, float* __restrict__ C, int n) {
    __shared__ float As[32 * 128];
    __shared__ float Bs[32 * 128];
    int tid = threadIdx.x;
    int r0 = blockIdx.x * 128;
    int tc = tid & 15, tr = tid >> 4;
    float acc[8][8] = {};

    for (int k0 = 0; k0 < F1; k0 += 32) {
        if (k0) __syncthreads();
        for (int idx = tid; idx < 128 * 8; idx += 256) {
            int row = idx & 127, kq = idx >> 7;
            int gr = r0 + row;
            if (gr >= n) gr = n - 1;
            float4 v = *(const float4*)(A + (size_t)gr * F1 + k0 + 4 * kq);
            As[(4 * kq + 0) * 128 + row] = v.x;
            As[(4 * kq + 1) * 128 + row] = v.y;
            As[(4 * kq + 2) * 128 + row] = v.z;
            As[(4 * kq + 3) * 128 + row] = v.w;
        }
        for (int idx = tid; idx < 32 * 32; idx += 256) {
            int k = idx >> 5, cq = idx & 31;
            *(float4*)(Bs + k * 128 + 4 * cq) =
                *(const float4*)(W + (size_t)(k0 + k) * F2 + 4 * cq);
        }
        __syncthreads();
#pragma unroll 4
        for (int k = 0; k < 32; k++) {
            float4 a0 = *(const float4*)(As + k * 128 + 4 * tr);
            float4 a1 = *(const float4*)(As + k * 128 + 64 + 4 * tr);
            float4 b0 = *(const float4*)(Bs + k * 128 + 4 * tc);
            float4 b1 = *(const float4*)(Bs + k * 128 + 64 + 4 * tc);
            float av[8] = {a0.x, a0.y, a0.z, a0.w, a1.x, a1.y, a1.z, a1.w};
            float bv[8] = {b0.x, b0.y, b0.z, b0.w, b1.x, b1.y, b1.z, b1.w};
#pragma unroll
            for (int i = 0; i < 8; i++)
#pragma unroll
                for (int j = 0; j < 8; j++) acc[i][j] += av[i] * bv[j];
        }
    }
    int ch = tc >> 2;             // chunk of columns 4*tc (0..3)
    int of = (tc & 3) << 2;       // float4 offset inside 16-float chunk row
#pragma unroll
    for (int i = 0; i < 8; i++) {
        int row = (i < 4) ? (4 * tr + i) : (64 + 4 * tr + i - 4);
        int gr = r0 + row;
        if (gr < n) {
            float d = dinv[gr];
            float4 o0 = {acc[i][0] * d, acc[i][1] * d, acc[i][2] * d, acc[i][3] * d};
            float4 o1 = {acc[i][4] * d, acc[i][5] * d, acc[i][6] * d, acc[i][7] * d};
            *(float4*)(C + ((size_t)ch * n + gr) * 16 + of) = o0;        // cols 4tc..
            *(float4*)(C + ((size_t)(ch + 4) * n + gr) * 16 + of) = o1;  // cols 64+4tc..
        }
    }
}

// ---------------- launch ----------------

static inline size_t align16(size_t x) { return (x + 3) & ~(size_t)3; }  // in 4B elems

extern "C" void kernel_launch(void* const* d_in, const int* in_sizes, int n_in,
                              void* d_out, int out_size, void* d_ws, size_t ws_size,
                              hipStream_t stream) {
    const float* x   = (const float*)d_in[0];
    const int*   ei  = (const int*)d_in[1];
    const float* W1  = (const float*)d_in[2];
    const float* b1  = (const float*)d_in[3];
    const float* W2  = (const float*)d_in[4];
    const float* b2  = (const float*)d_in[5];
    const float* Wfc = (const float*)d_in[6];
    const float* bfc = (const float*)d_in[7];
    float* out = (float*)d_out;

    const int n = in_sizes[0] / F0;   // 50000
    const int e = in_sizes[1] / 2;    // 800000
    const int* src = ei;
    const int* dst = ei + e;

    // workspace layout (4-byte elements, each region 16B-aligned)
    char* wsb = (char*)d_ws;
    size_t off = 0;
    int* deg    = (int*)(wsb + 4 * off); off = align16(off + n);
    int* excl   = (int*)(wsb + 4 * off); off = align16(off + n);
    int* bsum   = (int*)(wsb + 4 * off); off = align16(off + 256);
    int* rowptr = (int*)(wsb + 4 * off); off = align16(off + n + 1);
    int* cursor = (int*)(wsb + 4 * off); off = align16(off + n);
    int* csr    = (int*)(wsb + 4 * off); off = align16(off + e);
    float* dinv = (float*)(wsb + 4 * off); off = align16(off + n);
    float* xs   = (float*)(wsb + 4 * off); off = align16(off + (size_t)n * F0);
    float* aggX = (float*)(wsb + 4 * off); off = align16(off + (size_t)n * F0);
    float* a1   = (float*)(wsb + 4 * off); off = align16(off + (size_t)n * F1);
    float* h2c  = (float*)(wsb + 4 * off); off = align16(off + (size_t)n * F2);

    const int B = 256;
    const int nb = (n + B - 1) / B;        // 196 (<= 256)
    const int rblocks = (n + 127) / 128;

    // CSR build + scaled-x table; prefill out with bfc for chunked atomics
    zero_i32<<<nb, B, 0, stream>>>(deg, n);
    fill_f32<<<nb, B, 0, stream>>>(out, bfc, n);
    deg_count_i<<<(e + B - 1) / B, B, 0, stream>>>(dst, deg, e);
    scan1<<<nb, B, 0, stream>>>(deg, excl, bsum, dinv, n);
    scale_x<<<((n * 25) + B - 1) / B, B, 0, stream>>>(
        (const float4*)x, dinv, (float4*)xs, n * 25);
    scan2<<<1, B, 0, stream>>>(bsum, nb, rowptr, n);
    scan3<<<nb, B, 0, stream>>>(excl, bsum, rowptr, cursor, n);
    csr_fill<<<(e + B - 1) / B, B, 0, stream>>>(src, dst, cursor, csr, e);

    // layer 1: pull-aggregate xs, then tiled GEMM + bias + relu
    pull_f100<<<(n + 3) / 4, 256, 0, stream>>>(xs, rowptr, csr, dinv, aggX, n);
    gemm1_tiled<<<dim3(rblocks, F1 / 128), 256, 0, stream>>>(aggX, W1, b1, a1, n);

    // layer 2: tiled GEMM -> chunk-major pre-scaled h2c, then XCD-pinned
    // chunked pull (LDS-staged csr, batch-4 pipelined gathers) + epilogue
    gemm2_tiled<<<rblocks, 256, 0, stream>>>(a1, W2, dinv, h2c, n);
    pull_c16_fused<<<8 * ((n + 63) / 64), 256, 0, stream>>>(
        h2c, rowptr, csr, dinv, b2, Wfc, out, n);
}

// Round 5
// 346.590 us; speedup vs baseline: 1.3420x; 1.1239x over previous
//
#include <hip/hip_runtime.h>
#include <hip/hip_bf16.h>

// GCN: out = relu(gcnconv(relu(gcnconv(x,W1,b1)), W2, b2)) @ Wfc + bfc
// N=50000, E=800000, F0=100, F1=256, F2=128.
// Round 15: gathers are at their random-line-request ceiling (r10-r14:
// unchunked 64.5 us vs L2-resident chunked 67-69 us — both ~5 lines/cy/XCD).
// Attack the fp32 GEMMs instead (no fp32 MFMA on CDNA4): split-fp16 MFMA,
// 3-term a*b ~= ah*bh + ah*bl + al*bh on mfma_f32_16x16x32_f16 (fp32 acc).
// fp16 hi/lo products are exact in fp32; dropped lo*lo <= 2^-22 rel (~1e-6)
// — far below the passing absmax 6.1e-5 (plain bf16 = 4e-3, r4 failure).
// Producers emit hi/lo fp16 directly; workspace unions keep peak ~82 MB.
// Layer-2 pull kept from r14 (XCD-pinned chunk-major h2c, LDS-staged csr).

#define F0 100
#define F1 256
#define F2 128
#define CAP 2048

typedef _Float16 f16x4 __attribute__((ext_vector_type(4)));
typedef _Float16 f16x8 __attribute__((ext_vector_type(8)));
typedef float f32x4 __attribute__((ext_vector_type(4)));

// ---------------- CSR construction ----------------

__global__ void zero_i32(int* p, int n) {
    int i = blockIdx.x * blockDim.x + threadIdx.x;
    if (i < n) p[i] = 0;
}

__global__ void fill_f32(float* out, const float* __restrict__ bfc, int n) {
    int i = blockIdx.x * blockDim.x + threadIdx.x;
    if (i < n) out[i] = bfc[0];
}

__global__ void deg_count_i(const int* __restrict__ dst, int* deg, int e) {
    int i = blockIdx.x * blockDim.x + threadIdx.x;
    if (i < e) atomicAdd(deg + dst[i], 1);
}

__global__ __launch_bounds__(256) void scan1(const int* __restrict__ deg,
                                             int* __restrict__ excl,
                                             int* __restrict__ bsum,
                                             float* __restrict__ dinv, int n) {
    __shared__ int wsum[4];
    int i = blockIdx.x * 256 + threadIdx.x;
    int lane = threadIdx.x & 63, wid = threadIdx.x >> 6;
    int v = (i < n) ? deg[i] : 0;
    if (i < n) dinv[i] = rsqrtf((float)(v + 1));
    int s = v;
#pragma unroll
    for (int off = 1; off < 64; off <<= 1) {
        int t = __shfl_up(s, off, 64);
        if (lane >= off) s += t;
    }
    if (lane == 63) wsum[wid] = s;
    __syncthreads();
    int add = 0;
    for (int w = 0; w < wid; w++) add += wsum[w];
    if (i < n) excl[i] = add + s - v;
    if (threadIdx.x == 255) bsum[blockIdx.x] = add + s;
}

__global__ __launch_bounds__(256) void scan2(int* __restrict__ bsum, int nb,
                                             int* __restrict__ rowptr, int n) {
    __shared__ int wsum[4];
    int lane = threadIdx.x & 63, wid = threadIdx.x >> 6;
    int v = (threadIdx.x < nb) ? bsum[threadIdx.x] : 0;
    int s = v;
#pragma unroll
    for (int off = 1; off < 64; off <<= 1) {
        int t = __shfl_up(s, off, 64);
        if (lane >= off) s += t;
    }
    if (lane == 63) wsum[wid] = s;
    __syncthreads();
    int add = 0;
    for (int w = 0; w < wid; w++) add += wsum[w];
    if (threadIdx.x < nb) bsum[threadIdx.x] = add + s - v;
    if (threadIdx.x == 255) rowptr[n] = add + s;
}

__global__ void scan3(const int* __restrict__ excl, const int* __restrict__ bsum,
                      int* __restrict__ rowptr, int* __restrict__ cursor, int n) {
    int i = blockIdx.x * 256 + threadIdx.x;
    if (i < n) {
        int r = excl[i] + bsum[blockIdx.x];
        rowptr[i] = r;
        cursor[i] = r;
    }
}

__global__ void csr_fill(const int* __restrict__ src, const int* __restrict__ dst,
                         int* cursor, int* __restrict__ csr, int e) {
    int i = blockIdx.x * blockDim.x + threadIdx.x;
    if (i < e) {
        int pos = atomicAdd(cursor + dst[i], 1);
        csr[pos] = src[i];
    }
}

// xs = dinv[row] * x
__global__ void scale_x(const float4* __restrict__ x4,
                        const float* __restrict__ dinv,
                        float4* __restrict__ xs4, int n25) {
    int i = blockIdx.x * blockDim.x + threadIdx.x;
    if (i < n25) {
        float d = dinv[i / 25];
        float4 v = x4[i];
        v.x *= d; v.y *= d; v.z *= d; v.w *= d;
        xs4[i] = v;
    }
}

// W1t_h/l: [256][128] = W1^T zero-padded K 100->128, split fp16 hi/lo.
// W2t_h/l: [128][256] = W2^T, split fp16 hi/lo.
__global__ void wprep(const float* __restrict__ W1, const float* __restrict__ W2,
                      _Float16* __restrict__ W1h, _Float16* __restrict__ W1l,
                      _Float16* __restrict__ W2h, _Float16* __restrict__ W2l) {
    int i = blockIdx.x * 256 + threadIdx.x;
    if (i < 256 * 128) {
        int c = i >> 7, k = i & 127;
        float v = (k < F0) ? W1[(size_t)k * F1 + c] : 0.f;
        _Float16 h = (_Float16)v;
        W1h[i] = h;
        W1l[i] = (_Float16)(v - (float)h);
    } else if (i < 256 * 128 + 128 * 256) {
        int j = i - 256 * 128;
        int c = j >> 8, k = j & 255;
        float v = W2[(size_t)k * F2 + c];
        _Float16 h = (_Float16)v;
        W2h[j] = h;
        W2l[j] = (_Float16)(v - (float)h);
    }
}

// ---------------- layer-1 pull aggregation -> split-fp16 aggX -------------

// aggX[v][:] = dinv[v] * sum xs[s][:], emitted as fp16 hi/lo [n][128]
// (cols 100..127 zero). One wave/node; lanes 0-24 even edges, 32-56 odd.
__global__ __launch_bounds__(256) void pull_f100(
        const float* __restrict__ xs, const int* __restrict__ rowptr,
        const int* __restrict__ csr, const float* __restrict__ dinv,
        _Float16* __restrict__ aggh, _Float16* __restrict__ aggl, int n) {
    int wave = threadIdx.x >> 6, lane = threadIdx.x & 63;
    int v = blockIdx.x * 4 + wave;
    if (v >= n) return;
    int beg = rowptr[v], end = rowptr[v + 1];
    float dv = dinv[v];
    int half = lane >> 5, q = lane & 31;
    bool act = q < 25;
    float4 acc = {0.f, 0.f, 0.f, 0.f};
    if (half == 0 && act) acc = ((const float4*)(xs + (size_t)v * F0))[q];  // self

    for (int base = beg; base < end; base += 64) {
        int cnt = min(64, end - base);
        int sidx = (lane < cnt) ? csr[base + lane] : 0;
        int npf = cnt >> 1;
        int p = 0;
        for (; p + 4 <= npf; p += 4) {
            int s0 = __shfl(sidx, 2 * p + half, 64);
            int s1 = __shfl(sidx, 2 * p + 2 + half, 64);
            int s2 = __shfl(sidx, 2 * p + 4 + half, 64);
            int s3 = __shfl(sidx, 2 * p + 6 + half, 64);
            if (act) {
                float4 r0 = ((const float4*)(xs + (size_t)s0 * F0))[q];
                float4 r1 = ((const float4*)(xs + (size_t)s1 * F0))[q];
                float4 r2 = ((const float4*)(xs + (size_t)s2 * F0))[q];
                float4 r3 = ((const float4*)(xs + (size_t)s3 * F0))[q];
                acc.x += (r0.x + r1.x) + (r2.x + r3.x);
                acc.y += (r0.y + r1.y) + (r2.y + r3.y);
                acc.z += (r0.z + r1.z) + (r2.z + r3.z);
                acc.w += (r0.w + r1.w) + (r2.w + r3.w);
            }
        }
        for (; p < npf; p++) {
            int s0 = __shfl(sidx, 2 * p + half, 64);
            if (act) {
                float4 r0 = ((const float4*)(xs + (size_t)s0 * F0))[q];
                acc.x += r0.x; acc.y += r0.y; acc.z += r0.z; acc.w += r0.w;
            }
        }
        if (cnt & 1) {
            int sl = __shfl(sidx, cnt - 1, 64);
            if (half == 0 && act) {
                float4 r = ((const float4*)(xs + (size_t)sl * F0))[q];
                acc.x += r.x; acc.y += r.y; acc.z += r.z; acc.w += r.w;
            }
        }
    }
    float ox = __shfl_down(acc.x, 32, 64);
    float oy = __shfl_down(acc.y, 32, 64);
    float oz = __shfl_down(acc.z, 32, 64);
    float ow = __shfl_down(acc.w, 32, 64);
    if (half == 0) {
        float4 r = {0.f, 0.f, 0.f, 0.f};
        if (act) {
            r.x = dv * (acc.x + ox);
            r.y = dv * (acc.y + oy);
            r.z = dv * (acc.z + oz);
            r.w = dv * (acc.w + ow);
        }
        f16x4 hh, ll;
        hh[0] = (_Float16)r.x; ll[0] = (_Float16)(r.x - (float)hh[0]);
        hh[1] = (_Float16)r.y; ll[1] = (_Float16)(r.y - (float)hh[1]);
        hh[2] = (_Float16)r.z; ll[2] = (_Float16)(r.z - (float)hh[2]);
        hh[3] = (_Float16)r.w; ll[3] = (_Float16)(r.w - (float)hh[3]);
        *(f16x4*)(aggh + (size_t)v * 128 + 4 * q) = hh;
        *(f16x4*)(aggl + (size_t)v * 128 + 4 * q) = ll;
    }
}

// ---------------- split-fp16 MFMA GEMMs ----------------
// Tile 128x128, 4 waves (2x2), each wave 64x64 = 4x4 mfma_16x16x32 frags.
// LDS tiles [128][40] fp16 (pad 32->40: 80 B row stride, 16B-aligned,
// 2-way-bank-free b128 reads). A/B frag: row/col = lane&15, k = (lane>>4)*8.
// C frag: col = lane&15, row = (lane>>4)*4 + reg  [learn_hip m89].

// gemm1: a1 = relu(aggX @ W1t^T + b1) -> split fp16 h/l [n][256]. K=128.
__global__ __launch_bounds__(256) void gemm1_mfma(
        const _Float16* __restrict__ Ah, const _Float16* __restrict__ Al,
        const _Float16* __restrict__ Bh, const _Float16* __restrict__ Bl,
        const float* __restrict__ bias,
        _Float16* __restrict__ Ch, _Float16* __restrict__ Cl, int n) {
    __shared__ _Float16 sAh[128][40], sAl[128][40], sBh[128][40], sBl[128][40];
    int tid = threadIdx.x, lane = tid & 63, wave = tid >> 6;
    int wm = wave >> 1, wn = wave & 1;
    int r0 = blockIdx.x * 128, c0 = blockIdx.y * 128;
    int lr = lane & 15, ks8 = (lane >> 4) * 8;
    f32x4 acc[4][4] = {};

    for (int k0 = 0; k0 < 128; k0 += 32) {
        if (k0) __syncthreads();
#pragma unroll
        for (int p = 0; p < 2; ++p) {
            int u = tid + p * 256;
            int row = u >> 2, vv = u & 3;
            int gr = min(r0 + row, n - 1);
            *(f16x8*)&sAh[row][vv * 8] = *(const f16x8*)(Ah + (size_t)gr * 128 + k0 + vv * 8);
            *(f16x8*)&sAl[row][vv * 8] = *(const f16x8*)(Al + (size_t)gr * 128 + k0 + vv * 8);
            *(f16x8*)&sBh[row][vv * 8] = *(const f16x8*)(Bh + (size_t)(c0 + row) * 128 + k0 + vv * 8);
            *(f16x8*)&sBl[row][vv * 8] = *(const f16x8*)(Bl + (size_t)(c0 + row) * 128 + k0 + vv * 8);
        }
        __syncthreads();
        f16x8 a_h[4], a_l[4], b_h[4], b_l[4];
#pragma unroll
        for (int f = 0; f < 4; ++f) {
            a_h[f] = *(const f16x8*)&sAh[wm * 64 + f * 16 + lr][ks8];
            a_l[f] = *(const f16x8*)&sAl[wm * 64 + f * 16 + lr][ks8];
            b_h[f] = *(const f16x8*)&sBh[wn * 64 + f * 16 + lr][ks8];
            b_l[f] = *(const f16x8*)&sBl[wn * 64 + f * 16 + lr][ks8];
        }
#pragma unroll
        for (int i = 0; i < 4; ++i)
#pragma unroll
            for (int j = 0; j < 4; ++j) {
                acc[i][j] = __builtin_amdgcn_mfma_f32_16x16x32_f16(a_l[i], b_h[j], acc[i][j], 0, 0, 0);
                acc[i][j] = __builtin_amdgcn_mfma_f32_16x16x32_f16(a_h[i], b_l[j], acc[i][j], 0, 0, 0);
                acc[i][j] = __builtin_amdgcn_mfma_f32_16x16x32_f16(a_h[i], b_h[j], acc[i][j], 0, 0, 0);
            }
    }
#pragma unroll
    for (int j = 0; j < 4; ++j) {
        int col = c0 + wn * 64 + j * 16 + lr;
        float bv = bias[col];
#pragma unroll
        for (int i = 0; i < 4; ++i) {
            int rbase = r0 + wm * 64 + i * 16 + (lane >> 4) * 4;
#pragma unroll
            for (int r = 0; r < 4; ++r) {
                int gr = rbase + r;
                if (gr < n) {
                    float vv = fmaxf(acc[i][j][r] + bv, 0.f);
                    _Float16 h = (_Float16)vv;
                    Ch[(size_t)gr * 256 + col] = h;
                    Cl[(size_t)gr * 256 + col] = (_Float16)(vv - (float)h);
                }
            }
        }
    }
}

// gemm2: h2c = dinv[row] * (a1 @ W2t^T), K=256, N=128, chunk-major fp32 out.
__global__ __launch_bounds__(256) void gemm2_mfma(
        const _Float16* __restrict__ Ah, const _Float16* __restrict__ Al,
        const _Float16* __restrict__ Bh, const _Float16* __restrict__ Bl,
        const float* __restrict__ dinv, float* __restrict__ C, int n) {
    __shared__ _Float16 sAh[128][40], sAl[128][40], sBh[128][40], sBl[128][40];
    int tid = threadIdx.x, lane = tid & 63, wave = tid >> 6;
    int wm = wave >> 1, wn = wave & 1;
    int r0 = blockIdx.x * 128;
    int lr = lane & 15, ks8 = (lane >> 4) * 8;
    f32x4 acc[4][4] = {};

    for (int k0 = 0; k0 < 256; k0 += 32) {
        if (k0) __syncthreads();
#pragma unroll
        for (int p = 0; p < 2; ++p) {
            int u = tid + p * 256;
            int row = u >> 2, vv = u & 3;
            int gr = min(r0 + row, n - 1);
            *(f16x8*)&sAh[row][vv * 8] = *(const f16x8*)(Ah + (size_t)gr * 256 + k0 + vv * 8);
            *(f16x8*)&sAl[row][vv * 8] = *(const f16x8*)(Al + (size_t)gr * 256 + k0 + vv * 8);
            *(f16x8*)&sBh[row][vv * 8] = *(const f16x8*)(Bh + (size_t)row * 256 + k0 + vv * 8);
            *(f16x8*)&sBl[row][vv * 8] = *(const f16x8*)(Bl + (size_t)row * 256 + k0 + vv * 8);
        }
        __syncthreads();
        f16x8 a_h[4], a_l[4], b_h[4], b_l[4];
#pragma unroll
        for (int f = 0; f < 4; ++f) {
            a_h[f] = *(const f16x8*)&sAh[wm * 64 + f * 16 + lr][ks8];
            a_l[f] = *(const f16x8*)&sAl[wm * 64 + f * 16 + lr][ks8];
            b_h[f] = *(const f16x8*)&sBh[wn * 64 + f * 16 + lr][ks8];
            b_l[f] = *(const f16x8*)&sBl[wn * 64 + f * 16 + lr][ks8];
        }
#pragma unroll
        for (int i = 0; i < 4; ++i)
#pragma unroll
            for (int j = 0; j < 4; ++j) {
                acc[i][j] = __builtin_amdgcn_mfma_f32_16x16x32_f16(a_l[i], b_h[j], acc[i][j], 0, 0, 0);
                acc[i][j] = __builtin_amdgcn_mfma_f32_16x16x32_f16(a_h[i], b_l[j], acc[i][j], 0, 0, 0);
                acc[i][j] = __builtin_amdgcn_mfma_f32_16x16x32_f16(a_h[i], b_h[j], acc[i][j], 0, 0, 0);
            }
    }
#pragma unroll
    for (int j = 0; j < 4; ++j) {
        int chunk = wn * 4 + j;   // (col>>4); col&15 == lr
#pragma unroll
        for (int i = 0; i < 4; ++i) {
            int rbase = r0 + wm * 64 + i * 16 + (lane >> 4) * 4;
#pragma unroll
            for (int r = 0; r < 4; ++r) {
                int gr = rbase + r;
                if (gr < n) {
                    float d = dinv[gr];
                    C[((size_t)chunk * n + gr) * 16 + lr] = acc[i][j][r] * d;
                }
            }
        }
    }
}

// ---------------- layer-2 fused pull (r14, kept) ----------------

__global__ __launch_bounds__(256) void pull_c16_fused(
        const float* __restrict__ h2c, const int* __restrict__ rowptr,
        const int* __restrict__ csr, const float* __restrict__ dinv,
        const float* __restrict__ b2, const float* __restrict__ Wfc,
        float* __restrict__ out, int n) {
    __shared__ int s_row[65];
    __shared__ float s_dinv[64];
    __shared__ int s_csr[CAP];
    int chunk = blockIdx.x & 7;
    int nb = blockIdx.x >> 3;
    int v0 = nb * 64;
    int tid = threadIdx.x;
    int lane = tid & 63, wv = tid >> 6;
    int q = lane & 3;
    int g2 = (lane >> 2) & 3;
    int grp = lane >> 4;
    const float* __restrict__ tab = h2c + (size_t)chunk * n * 16;

    if (tid <= 64) s_row[tid] = rowptr[min(v0 + tid, n)];
    if (tid < 64) s_dinv[tid] = (v0 + tid < n) ? dinv[v0 + tid] : 0.f;
    __syncthreads();
    int ebeg = s_row[0], eend = s_row[64];

    int base_local = wv * 16 + grp * 4;

    float4 acc[4];
#pragma unroll
    for (int nn = 0; nn < 4; ++nn) acc[nn] = (float4){0.f, 0.f, 0.f, 0.f};

#pragma unroll
    for (int nn = 0; nn < 4; ++nn) {
        int node = v0 + base_local + nn;
        if (node < n && g2 == 0)
            acc[nn] = ((const float4*)(tab + (size_t)node * 16))[q];
    }

    for (int w0 = ebeg; w0 < eend; w0 += CAP) {
        int wcnt = min(CAP, eend - w0);
        if (w0 != ebeg) __syncthreads();
        for (int i = tid; i < wcnt; i += 256)
            s_csr[i] = __builtin_nontemporal_load(csr + w0 + i);
        __syncthreads();
#pragma unroll
        for (int nn = 0; nn < 4; ++nn) {
            int local = base_local + nn;
            int nbg = max(s_row[local], w0) - w0;
            int nen = min(s_row[local + 1], w0 + wcnt) - w0;
            for (int t = nbg + 4 * g2; t < nen; t += 16) {
                int i1 = min(t + 1, nen - 1);
                int i2 = min(t + 2, nen - 1);
                int i3 = min(t + 3, nen - 1);
                int s0 = s_csr[t];
                int s1 = s_csr[i1];
                int s2 = s_csr[i2];
                int s3 = s_csr[i3];
                float4 r0 = ((const float4*)(tab + (size_t)s0 * 16))[q];
                float4 r1 = ((const float4*)(tab + (size_t)s1 * 16))[q];
                float4 r2 = ((const float4*)(tab + (size_t)s2 * 16))[q];
                float4 r3 = ((const float4*)(tab + (size_t)s3 * 16))[q];
                bool m1 = (t + 1 < nen), m2 = (t + 2 < nen), m3 = (t + 3 < nen);
                acc[nn].x += r0.x + (m1 ? r1.x : 0.f);
                acc[nn].y += r0.y + (m1 ? r1.y : 0.f);
                acc[nn].z += r0.z + (m1 ? r1.z : 0.f);
                acc[nn].w += r0.w + (m1 ? r1.w : 0.f);
                acc[nn].x += (m2 ? r2.x : 0.f) + (m3 ? r3.x : 0.f);
                acc[nn].y += (m2 ? r2.y : 0.f) + (m3 ? r3.y : 0.f);
                acc[nn].z += (m2 ? r2.z : 0.f) + (m3 ? r3.z : 0.f);
                acc[nn].w += (m2 ? r2.w : 0.f) + (m3 ? r3.w : 0.f);
            }
        }
    }

    int c0 = chunk * 16 + 4 * q;
    float4 bb = *(const float4*)(b2 + c0);
    float4 ww = *(const float4*)(Wfc + c0);
#pragma unroll
    for (int nn = 0; nn < 4; ++nn) {
        int local = base_local + nn;
        int node = v0 + local;
        float dv = s_dinv[local];
        float4 a = acc[nn];
        a.x += __shfl_xor(a.x, 4, 64);
        a.y += __shfl_xor(a.y, 4, 64);
        a.z += __shfl_xor(a.z, 4, 64);
        a.w += __shfl_xor(a.w, 4, 64);
        a.x += __shfl_xor(a.x, 8, 64);
        a.y += __shfl_xor(a.y, 8, 64);
        a.z += __shfl_xor(a.z, 8, 64);
        a.w += __shfl_xor(a.w, 8, 64);
        float part = fmaxf(fmaf(dv, a.x, bb.x), 0.f) * ww.x
                   + fmaxf(fmaf(dv, a.y, bb.y), 0.f) * ww.y
                   + fmaxf(fmaf(dv, a.z, bb.z), 0.f) * ww.z
                   + fmaxf(fmaf(dv, a.w, bb.w), 0.f) * ww.w;
        part += __shfl_xor(part, 1, 64);
        part += __shfl_xor(part, 2, 64);
        if (node < n && (lane & 15) == 0) atomicAdd(out + node, part);
    }
}

// ---------------- launch ----------------

extern "C" void kernel_launch(void* const* d_in, const int* in_sizes, int n_in,
                              void* d_out, int out_size, void* d_ws, size_t ws_size,
                              hipStream_t stream) {
    const float* x   = (const float*)d_in[0];
    const int*   ei  = (const int*)d_in[1];
    const float* W1  = (const float*)d_in[2];
    const float* b1  = (const float*)d_in[3];
    const float* W2  = (const float*)d_in[4];
    const float* b2  = (const float*)d_in[5];
    const float* Wfc = (const float*)d_in[6];
    const float* bfc = (const float*)d_in[7];
    float* out = (float*)d_out;

    const int n = in_sizes[0] / F0;   // 50000
    const int e = in_sizes[1] / 2;    // 800000
    const int* src = ei;
    const int* dst = ei + e;

    // workspace (byte offsets, 256-B aligned regions, lifetime unions)
    char* wsb = (char*)d_ws;
    size_t off = 0;
    auto alloc = [&](size_t bytes) -> void* {
        off = (off + 255) & ~(size_t)255;
        void* r = wsb + off;
        off += bytes;
        return r;
    };
    int* deg    = (int*)alloc((size_t)n * 4);
    int* excl   = (int*)alloc((size_t)n * 4);
    int* bsum   = (int*)alloc(1024);
    int* rowptr = (int*)alloc((size_t)(n + 1) * 4);
    int* cursor = (int*)alloc((size_t)n * 4);
    int* csr    = (int*)alloc((size_t)e * 4);
    float* dinv = (float*)alloc((size_t)n * 4);
    _Float16* W1h = (_Float16*)alloc(256 * 128 * 2);
    _Float16* W1l = (_Float16*)alloc(256 * 128 * 2);
    _Float16* W2h = (_Float16*)alloc(128 * 256 * 2);
    _Float16* W2l = (_Float16*)alloc(128 * 256 * 2);
    // bufA: xs (n*100 f32) THEN a1h+a1l (2 * n*256 f16); xs dead before gemm1
    char* bufA = (char*)alloc((size_t)n * 256 * 2 * 2);
    float* xs = (float*)bufA;
    _Float16* a1h = (_Float16*)bufA;
    _Float16* a1l = a1h + (size_t)n * 256;
    // bufB: aggXh+aggXl (2 * n*128 f16) THEN h2c (n*128 f32); aggX dead before gemm2
    char* bufB = (char*)alloc((size_t)n * 128 * 4);
    _Float16* aggh = (_Float16*)bufB;
    _Float16* aggl = aggh + (size_t)n * 128;
    float* h2c = (float*)bufB;

    const int B = 256;
    const int nb = (n + B - 1) / B;
    const int rblocks = (n + 127) / 128;

    zero_i32<<<nb, B, 0, stream>>>(deg, n);
    fill_f32<<<nb, B, 0, stream>>>(out, bfc, n);
    deg_count_i<<<(e + B - 1) / B, B, 0, stream>>>(dst, deg, e);
    scan1<<<nb, B, 0, stream>>>(deg, excl, bsum, dinv, n);
    scale_x<<<((n * 25) + B - 1) / B, B, 0, stream>>>(
        (const float4*)x, dinv, (float4*)xs, n * 25);
    wprep<<<256, 256, 0, stream>>>(W1, W2, W1h, W1l, W2h, W2l);
    scan2<<<1, B, 0, stream>>>(bsum, nb, rowptr, n);
    scan3<<<nb, B, 0, stream>>>(excl, bsum, rowptr, cursor, n);
    csr_fill<<<(e + B - 1) / B, B, 0, stream>>>(src, dst, cursor, csr, e);

    // layer 1: pull-aggregate xs -> split-fp16 aggX, then MFMA GEMM
    pull_f100<<<(n + 3) / 4, 256, 0, stream>>>(xs, rowptr, csr, dinv, aggh, aggl, n);
    gemm1_mfma<<<dim3(rblocks, 2), 256, 0, stream>>>(aggh, aggl, W1h, W1l, b1,
                                                     a1h, a1l, n);
    // layer 2: MFMA GEMM -> chunk-major fp32 h2c, then fused pull
    gemm2_mfma<<<rblocks, 256, 0, stream>>>(a1h, a1l, W2h, W2l, dinv, h2c, n);
    pull_c16_fused<<<8 * ((n + 63) / 64), 256, 0, stream>>>(
        h2c, rowptr, csr, dinv, b2, Wfc, out, n);
}

// Round 6
// 343.522 us; speedup vs baseline: 1.3540x; 1.0089x over previous
//
#include <hip/hip_runtime.h>
#include <hip/hip_bf16.h>

// GCN: out = relu(gcnconv(relu(gcnconv(x,W1,b1)), W2, b2)) @ Wfc + bfc
// N=50000, E=800000, F0=100, F1=256, F2=128.
// Round 16: fuse the two split-fp16 MFMA GEMMs. r15 showed gemm1 at 60 us,
// 5.9% MfmaUtil, 1.5 TB/s — memory-shaped (h/l split = fp32 bytes) with a
// 102 MB a1 round-trip. Fused kernel: stage-1 a1 tile (128x256) lives in
// registers (acc1 64 VGPR/wave, 8 waves), MFMA operands DIRECT from global
// (A 16-line coalesced wave-loads, W1t/W2t L2-resident); stage-2 transposes
// a1 through a 68 KB LDS half-tile (h/l, [128][136] pad = conflict-free) and
// writes dinv-scaled chunk-major h2c. Traffic ~170->55 MB for the GEMM pair.
// 3-term split-fp16 everywhere: a*b ~= ah*bh + ah*bl + al*bh (fp32 acc).
// Layer-2 pull kept from r14 (XCD-pinned chunk-major h2c, LDS-staged csr).

#define F0 100
#define F1 256
#define F2 128
#define CAP 2048

typedef _Float16 f16x4 __attribute__((ext_vector_type(4)));
typedef _Float16 f16x8 __attribute__((ext_vector_type(8)));
typedef float f32x4 __attribute__((ext_vector_type(4)));

// ---------------- CSR construction ----------------

__global__ void zero_i32(int* p, int n) {
    int i = blockIdx.x * blockDim.x + threadIdx.x;
    if (i < n) p[i] = 0;
}

__global__ void fill_f32(float* out, const float* __restrict__ bfc, int n) {
    int i = blockIdx.x * blockDim.x + threadIdx.x;
    if (i < n) out[i] = bfc[0];
}

__global__ void deg_count_i(const int* __restrict__ dst, int* deg, int e) {
    int i = blockIdx.x * blockDim.x + threadIdx.x;
    if (i < e) atomicAdd(deg + dst[i], 1);
}

__global__ __launch_bounds__(256) void scan1(const int* __restrict__ deg,
                                             int* __restrict__ excl,
                                             int* __restrict__ bsum,
                                             float* __restrict__ dinv, int n) {
    __shared__ int wsum[4];
    int i = blockIdx.x * 256 + threadIdx.x;
    int lane = threadIdx.x & 63, wid = threadIdx.x >> 6;
    int v = (i < n) ? deg[i] : 0;
    if (i < n) dinv[i] = rsqrtf((float)(v + 1));
    int s = v;
#pragma unroll
    for (int off = 1; off < 64; off <<= 1) {
        int t = __shfl_up(s, off, 64);
        if (lane >= off) s += t;
    }
    if (lane == 63) wsum[wid] = s;
    __syncthreads();
    int add = 0;
    for (int w = 0; w < wid; w++) add += wsum[w];
    if (i < n) excl[i] = add + s - v;
    if (threadIdx.x == 255) bsum[blockIdx.x] = add + s;
}

__global__ __launch_bounds__(256) void scan2(int* __restrict__ bsum, int nb,
                                             int* __restrict__ rowptr, int n) {
    __shared__ int wsum[4];
    int lane = threadIdx.x & 63, wid = threadIdx.x >> 6;
    int v = (threadIdx.x < nb) ? bsum[threadIdx.x] : 0;
    int s = v;
#pragma unroll
    for (int off = 1; off < 64; off <<= 1) {
        int t = __shfl_up(s, off, 64);
        if (lane >= off) s += t;
    }
    if (lane == 63) wsum[wid] = s;
    __syncthreads();
    int add = 0;
    for (int w = 0; w < wid; w++) add += wsum[w];
    if (threadIdx.x < nb) bsum[threadIdx.x] = add + s - v;
    if (threadIdx.x == 255) rowptr[n] = add + s;
}

__global__ void scan3(const int* __restrict__ excl, const int* __restrict__ bsum,
                      int* __restrict__ rowptr, int* __restrict__ cursor, int n) {
    int i = blockIdx.x * 256 + threadIdx.x;
    if (i < n) {
        int r = excl[i] + bsum[blockIdx.x];
        rowptr[i] = r;
        cursor[i] = r;
    }
}

__global__ void csr_fill(const int* __restrict__ src, const int* __restrict__ dst,
                         int* cursor, int* __restrict__ csr, int e) {
    int i = blockIdx.x * blockDim.x + threadIdx.x;
    if (i < e) {
        int pos = atomicAdd(cursor + dst[i], 1);
        csr[pos] = src[i];
    }
}

// xs = dinv[row] * x
__global__ void scale_x(const float4* __restrict__ x4,
                        const float* __restrict__ dinv,
                        float4* __restrict__ xs4, int n25) {
    int i = blockIdx.x * blockDim.x + threadIdx.x;
    if (i < n25) {
        float d = dinv[i / 25];
        float4 v = x4[i];
        v.x *= d; v.y *= d; v.z *= d; v.w *= d;
        xs4[i] = v;
    }
}

// W1t_h/l: [256][128] = W1^T zero-padded K 100->128, split fp16 hi/lo.
// W2t_h/l: [128][256] = W2^T, split fp16 hi/lo.
__global__ void wprep(const float* __restrict__ W1, const float* __restrict__ W2,
                      _Float16* __restrict__ W1h, _Float16* __restrict__ W1l,
                      _Float16* __restrict__ W2h, _Float16* __restrict__ W2l) {
    int i = blockIdx.x * 256 + threadIdx.x;
    if (i < 256 * 128) {
        int c = i >> 7, k = i & 127;
        float v = (k < F0) ? W1[(size_t)k * F1 + c] : 0.f;
        _Float16 h = (_Float16)v;
        W1h[i] = h;
        W1l[i] = (_Float16)(v - (float)h);
    } else if (i < 256 * 128 + 128 * 256) {
        int j = i - 256 * 128;
        int c = j >> 8, k = j & 255;
        float v = W2[(size_t)k * F2 + c];
        _Float16 h = (_Float16)v;
        W2h[j] = h;
        W2l[j] = (_Float16)(v - (float)h);
    }
}

// ---------------- layer-1 pull aggregation -> split-fp16 aggX -------------

// aggX[v][:] = dinv[v] * sum xs[s][:], emitted as fp16 hi/lo [n][128]
// (cols 100..127 zero). One wave/node; lanes 0-24 even edges, 32-56 odd.
__global__ __launch_bounds__(256) void pull_f100(
        const float* __restrict__ xs, const int* __restrict__ rowptr,
        const int* __restrict__ csr, const float* __restrict__ dinv,
        _Float16* __restrict__ aggh, _Float16* __restrict__ aggl, int n) {
    int wave = threadIdx.x >> 6, lane = threadIdx.x & 63;
    int v = blockIdx.x * 4 + wave;
    if (v >= n) return;
    int beg = rowptr[v], end = rowptr[v + 1];
    float dv = dinv[v];
    int half = lane >> 5, q = lane & 31;
    bool act = q < 25;
    float4 acc = {0.f, 0.f, 0.f, 0.f};
    if (half == 0 && act) acc = ((const float4*)(xs + (size_t)v * F0))[q];  // self

    for (int base = beg; base < end; base += 64) {
        int cnt = min(64, end - base);
        int sidx = (lane < cnt) ? csr[base + lane] : 0;
        int npf = cnt >> 1;
        int p = 0;
        for (; p + 4 <= npf; p += 4) {
            int s0 = __shfl(sidx, 2 * p + half, 64);
            int s1 = __shfl(sidx, 2 * p + 2 + half, 64);
            int s2 = __shfl(sidx, 2 * p + 4 + half, 64);
            int s3 = __shfl(sidx, 2 * p + 6 + half, 64);
            if (act) {
                float4 r0 = ((const float4*)(xs + (size_t)s0 * F0))[q];
                float4 r1 = ((const float4*)(xs + (size_t)s1 * F0))[q];
                float4 r2 = ((const float4*)(xs + (size_t)s2 * F0))[q];
                float4 r3 = ((const float4*)(xs + (size_t)s3 * F0))[q];
                acc.x += (r0.x + r1.x) + (r2.x + r3.x);
                acc.y += (r0.y + r1.y) + (r2.y + r3.y);
                acc.z += (r0.z + r1.z) + (r2.z + r3.z);
                acc.w += (r0.w + r1.w) + (r2.w + r3.w);
            }
        }
        for (; p < npf; p++) {
            int s0 = __shfl(sidx, 2 * p + half, 64);
            if (act) {
                float4 r0 = ((const float4*)(xs + (size_t)s0 * F0))[q];
                acc.x += r0.x; acc.y += r0.y; acc.z += r0.z; acc.w += r0.w;
            }
        }
        if (cnt & 1) {
            int sl = __shfl(sidx, cnt - 1, 64);
            if (half == 0 && act) {
                float4 r = ((const float4*)(xs + (size_t)sl * F0))[q];
                acc.x += r.x; acc.y += r.y; acc.z += r.z; acc.w += r.w;
            }
        }
    }
    float ox = __shfl_down(acc.x, 32, 64);
    float oy = __shfl_down(acc.y, 32, 64);
    float oz = __shfl_down(acc.z, 32, 64);
    float ow = __shfl_down(acc.w, 32, 64);
    if (half == 0) {
        float4 r = {0.f, 0.f, 0.f, 0.f};
        if (act) {
            r.x = dv * (acc.x + ox);
            r.y = dv * (acc.y + oy);
            r.z = dv * (acc.z + oz);
            r.w = dv * (acc.w + ow);
        }
        f16x4 hh, ll;
        hh[0] = (_Float16)r.x; ll[0] = (_Float16)(r.x - (float)hh[0]);
        hh[1] = (_Float16)r.y; ll[1] = (_Float16)(r.y - (float)hh[1]);
        hh[2] = (_Float16)r.z; ll[2] = (_Float16)(r.z - (float)hh[2]);
        hh[3] = (_Float16)r.w; ll[3] = (_Float16)(r.w - (float)hh[3]);
        *(f16x4*)(aggh + (size_t)v * 128 + 4 * q) = hh;
        *(f16x4*)(aggl + (size_t)v * 128 + 4 * q) = ll;
    }
}

// ---------------- fused GEMM1+GEMM2 (split-fp16 MFMA) ----------------
// 8 waves (512 thr), M-tile 128. Wave grid (wm 0-1, wn 0-3).
// Stage 1: a1[128][256] = relu(aggX @ W1t^T + b1); wave quadrant 64x64 in
//   acc1[4][4] (fp32). Operands DIRECT from global: A-frags 16B/lane (16
//   fully-used 64B lines per wave-load), W1t from L2. No LDS, no barriers.
// Stage 2: for each 128-col half of a1: participating waves split h/l and
//   ds_write_b16 into sAh/sAl [128][136] (pad -> uniform 8 lanes per 4-bank
//   window = wave-minimum); all waves run K=128 MFMA chain with W2t frags
//   from L2 into acc2[4][2]; dinv-scale; chunk-major fp32 h2c write (64B
//   contiguous per 16 lanes).
// Frag layouts verified on HW in r15 (passed): A/B row|col = lane&15,
//   k = (lane>>4)*8; C col = lane&15, row = (lane>>4)*4 + reg.
__global__ __launch_bounds__(512) void gemm12_fused(
        const _Float16* __restrict__ Ah, const _Float16* __restrict__ Al,
        const _Float16* __restrict__ W1h, const _Float16* __restrict__ W1l,
        const _Float16* __restrict__ W2h, const _Float16* __restrict__ W2l,
        const float* __restrict__ b1, const float* __restrict__ dinv,
        float* __restrict__ C, int n) {
    __shared__ _Float16 sAh[128][136], sAl[128][136];   // 68 KB
    int tid = threadIdx.x, lane = tid & 63, wave = tid >> 6;
    int wm = wave >> 2, wn = wave & 3;
    int r0 = blockIdx.x * 128;
    int lr = lane & 15, kg = lane >> 4, ks8 = kg * 8;

    // ---- stage 1 ----
    f32x4 acc1[4][4] = {};
    int arow[4];
#pragma unroll
    for (int i = 0; i < 4; ++i) arow[i] = min(r0 + wm * 64 + i * 16 + lr, n - 1);

#pragma unroll
    for (int k0 = 0; k0 < 128; k0 += 32) {
        f16x8 a_h[4], a_l[4], b_h[4], b_l[4];
#pragma unroll
        for (int i = 0; i < 4; ++i) {
            a_h[i] = *(const f16x8*)(Ah + (size_t)arow[i] * 128 + k0 + ks8);
            a_l[i] = *(const f16x8*)(Al + (size_t)arow[i] * 128 + k0 + ks8);
        }
#pragma unroll
        for (int j = 0; j < 4; ++j) {
            int col = wn * 64 + j * 16 + lr;
            b_h[j] = *(const f16x8*)(W1h + (size_t)col * 128 + k0 + ks8);
            b_l[j] = *(const f16x8*)(W1l + (size_t)col * 128 + k0 + ks8);
        }
#pragma unroll
        for (int i = 0; i < 4; ++i)
#pragma unroll
            for (int j = 0; j < 4; ++j) {
                acc1[i][j] = __builtin_amdgcn_mfma_f32_16x16x32_f16(a_l[i], b_h[j], acc1[i][j], 0, 0, 0);
                acc1[i][j] = __builtin_amdgcn_mfma_f32_16x16x32_f16(a_h[i], b_l[j], acc1[i][j], 0, 0, 0);
                acc1[i][j] = __builtin_amdgcn_mfma_f32_16x16x32_f16(a_h[i], b_h[j], acc1[i][j], 0, 0, 0);
            }
    }
    // bias + relu
#pragma unroll
    for (int j = 0; j < 4; ++j) {
        float bv = b1[wn * 64 + j * 16 + lr];
#pragma unroll
        for (int i = 0; i < 4; ++i)
#pragma unroll
            for (int r = 0; r < 4; ++r)
                acc1[i][j][r] = fmaxf(acc1[i][j][r] + bv, 0.f);
    }

    // ---- stage 2: two 128-mid-col halves through LDS ----
    f32x4 acc2[4][2] = {};
#pragma unroll
    for (int half = 0; half < 2; ++half) {
        if (half) __syncthreads();          // all reads of prev half done
        if ((wn >> 1) == half) {
            int cb = (wn & 1) * 64;
#pragma unroll
            for (int i = 0; i < 4; ++i)
#pragma unroll
                for (int j = 0; j < 4; ++j)
#pragma unroll
                    for (int r = 0; r < 4; ++r) {
                        int row = wm * 64 + i * 16 + kg * 4 + r;
                        int col = cb + j * 16 + lr;
                        float v = acc1[i][j][r];
                        _Float16 h = (_Float16)v;
                        sAh[row][col] = h;
                        sAl[row][col] = (_Float16)(v - (float)h);
                    }
        }
        __syncthreads();
#pragma unroll
        for (int k0 = 0; k0 < 128; k0 += 32) {
            f16x8 a_h[4], a_l[4], b_h[2], b_l[2];
#pragma unroll
            for (int i = 0; i < 4; ++i) {
                a_h[i] = *(const f16x8*)&sAh[wm * 64 + i * 16 + lr][k0 + ks8];
                a_l[i] = *(const f16x8*)&sAl[wm * 64 + i * 16 + lr][k0 + ks8];
            }
#pragma unroll
            for (int j = 0; j < 2; ++j) {
                int col = wn * 32 + j * 16 + lr;
                int kk = half * 128 + k0 + ks8;
                b_h[j] = *(const f16x8*)(W2h + (size_t)col * 256 + kk);
                b_l[j] = *(const f16x8*)(W2l + (size_t)col * 256 + kk);
            }
#pragma unroll
            for (int i = 0; i < 4; ++i)
#pragma unroll
                for (int j = 0; j < 2; ++j) {
                    acc2[i][j] = __builtin_amdgcn_mfma_f32_16x16x32_f16(a_l[i], b_h[j], acc2[i][j], 0, 0, 0);
                    acc2[i][j] = __builtin_amdgcn_mfma_f32_16x16x32_f16(a_h[i], b_l[j], acc2[i][j], 0, 0, 0);
                    acc2[i][j] = __builtin_amdgcn_mfma_f32_16x16x32_f16(a_h[i], b_h[j], acc2[i][j], 0, 0, 0);
                }
        }
    }

    // ---- epilogue: dinv scale, chunk-major write ----
#pragma unroll
    for (int i = 0; i < 4; ++i)
#pragma unroll
        for (int r = 0; r < 4; ++r) {
            int gr = r0 + wm * 64 + i * 16 + kg * 4 + r;
            if (gr < n) {
                float d = dinv[gr];
#pragma unroll
                for (int j = 0; j < 2; ++j) {
                    int chunk = wn * 2 + j;
                    C[((size_t)chunk * n + gr) * 16 + lr] = acc2[i][j][r] * d;
                }
            }
        }
}

// ---------------- layer-2 fused pull (r14, kept) ----------------

__global__ __launch_bounds__(256) void pull_c16_fused(
        const float* __restrict__ h2c, const int* __restrict__ rowptr,
        const int* __restrict__ csr, const float* __restrict__ dinv,
        const float* __restrict__ b2, const float* __restrict__ Wfc,
        float* __restrict__ out, int n) {
    __shared__ int s_row[65];
    __shared__ float s_dinv[64];
    __shared__ int s_csr[CAP];
    int chunk = blockIdx.x & 7;
    int nb = blockIdx.x >> 3;
    int v0 = nb * 64;
    int tid = threadIdx.x;
    int lane = tid & 63, wv = tid >> 6;
    int q = lane & 3;
    int g2 = (lane >> 2) & 3;
    int grp = lane >> 4;
    const float* __restrict__ tab = h2c + (size_t)chunk * n * 16;

    if (tid <= 64) s_row[tid] = rowptr[min(v0 + tid, n)];
    if (tid < 64) s_dinv[tid] = (v0 + tid < n) ? dinv[v0 + tid] : 0.f;
    __syncthreads();
    int ebeg = s_row[0], eend = s_row[64];

    int base_local = wv * 16 + grp * 4;

    float4 acc[4];
#pragma unroll
    for (int nn = 0; nn < 4; ++nn) acc[nn] = (float4){0.f, 0.f, 0.f, 0.f};

#pragma unroll
    for (int nn = 0; nn < 4; ++nn) {
        int node = v0 + base_local + nn;
        if (node < n && g2 == 0)
            acc[nn] = ((const float4*)(tab + (size_t)node * 16))[q];
    }

    for (int w0 = ebeg; w0 < eend; w0 += CAP) {
        int wcnt = min(CAP, eend - w0);
        if (w0 != ebeg) __syncthreads();
        for (int i = tid; i < wcnt; i += 256)
            s_csr[i] = __builtin_nontemporal_load(csr + w0 + i);
        __syncthreads();
#pragma unroll
        for (int nn = 0; nn < 4; ++nn) {
            int local = base_local + nn;
            int nbg = max(s_row[local], w0) - w0;
            int nen = min(s_row[local + 1], w0 + wcnt) - w0;
            for (int t = nbg + 4 * g2; t < nen; t += 16) {
                int i1 = min(t + 1, nen - 1);
                int i2 = min(t + 2, nen - 1);
                int i3 = min(t + 3, nen - 1);
                int s0 = s_csr[t];
                int s1 = s_csr[i1];
                int s2 = s_csr[i2];
                int s3 = s_csr[i3];
                float4 r0 = ((const float4*)(tab + (size_t)s0 * 16))[q];
                float4 r1 = ((const float4*)(tab + (size_t)s1 * 16))[q];
                float4 r2 = ((const float4*)(tab + (size_t)s2 * 16))[q];
                float4 r3 = ((const float4*)(tab + (size_t)s3 * 16))[q];
                bool m1 = (t + 1 < nen), m2 = (t + 2 < nen), m3 = (t + 3 < nen);
                acc[nn].x += r0.x + (m1 ? r1.x : 0.f);
                acc[nn].y += r0.y + (m1 ? r1.y : 0.f);
                acc[nn].z += r0.z + (m1 ? r1.z : 0.f);
                acc[nn].w += r0.w + (m1 ? r1.w : 0.f);
                acc[nn].x += (m2 ? r2.x : 0.f) + (m3 ? r3.x : 0.f);
                acc[nn].y += (m2 ? r2.y : 0.f) + (m3 ? r3.y : 0.f);
                acc[nn].z += (m2 ? r2.z : 0.f) + (m3 ? r3.z : 0.f);
                acc[nn].w += (m2 ? r2.w : 0.f) + (m3 ? r3.w : 0.f);
            }
        }
    }

    int c0 = chunk * 16 + 4 * q;
    float4 bb = *(const float4*)(b2 + c0);
    float4 ww = *(const float4*)(Wfc + c0);
#pragma unroll
    for (int nn = 0; nn < 4; ++nn) {
        int local = base_local + nn;
        int node = v0 + local;
        float dv = s_dinv[local];
        float4 a = acc[nn];
        a.x += __shfl_xor(a.x, 4, 64);
        a.y += __shfl_xor(a.y, 4, 64);
        a.z += __shfl_xor(a.z, 4, 64);
        a.w += __shfl_xor(a.w, 4, 64);
        a.x += __shfl_xor(a.x, 8, 64);
        a.y += __shfl_xor(a.y, 8, 64);
        a.z += __shfl_xor(a.z, 8, 64);
        a.w += __shfl_xor(a.w, 8, 64);
        float part = fmaxf(fmaf(dv, a.x, bb.x), 0.f) * ww.x
                   + fmaxf(fmaf(dv, a.y, bb.y), 0.f) * ww.y
                   + fmaxf(fmaf(dv, a.z, bb.z), 0.f) * ww.z
                   + fmaxf(fmaf(dv, a.w, bb.w), 0.f) * ww.w;
        part += __shfl_xor(part, 1, 64);
        part += __shfl_xor(part, 2, 64);
        if (node < n && (lane & 15) == 0) atomicAdd(out + node, part);
    }
}

// ---------------- launch ----------------

extern "C" void kernel_launch(void* const* d_in, const int* in_sizes, int n_in,
                              void* d_out, int out_size, void* d_ws, size_t ws_size,
                              hipStream_t stream) {
    const float* x   = (const float*)d_in[0];
    const int*   ei  = (const int*)d_in[1];
    const float* W1  = (const float*)d_in[2];
    const float* b1  = (const float*)d_in[3];
    const float* W2  = (const float*)d_in[4];
    const float* b2  = (const float*)d_in[5];
    const float* Wfc = (const float*)d_in[6];
    const float* bfc = (const float*)d_in[7];
    float* out = (float*)d_out;

    const int n = in_sizes[0] / F0;   // 50000
    const int e = in_sizes[1] / 2;    // 800000
    const int* src = ei;
    const int* dst = ei + e;

    // workspace (byte offsets, 256-B aligned regions, lifetime unions)
    char* wsb = (char*)d_ws;
    size_t off = 0;
    auto alloc = [&](size_t bytes) -> void* {
        off = (off + 255) & ~(size_t)255;
        void* r = wsb + off;
        off += bytes;
        return r;
    };
    int* deg    = (int*)alloc((size_t)n * 4);
    int* excl   = (int*)alloc((size_t)n * 4);
    int* bsum   = (int*)alloc(1024);
    int* rowptr = (int*)alloc((size_t)(n + 1) * 4);
    int* cursor = (int*)alloc((size_t)n * 4);
    int* csr    = (int*)alloc((size_t)e * 4);
    float* dinv = (float*)alloc((size_t)n * 4);
    _Float16* W1h = (_Float16*)alloc(256 * 128 * 2);
    _Float16* W1l = (_Float16*)alloc(256 * 128 * 2);
    _Float16* W2h = (_Float16*)alloc(128 * 256 * 2);
    _Float16* W2l = (_Float16*)alloc(128 * 256 * 2);
    // bufA: xs (n*100 f32) THEN h2c (n*128 f32); xs dead before gemm12 writes
    char* bufA = (char*)alloc((size_t)n * 128 * 4);
    float* xs  = (float*)bufA;
    float* h2c = (float*)bufA;
    // aggX h/l: alive from pull_f100 through gemm12 — own region
    _Float16* aggh = (_Float16*)alloc((size_t)n * 128 * 2);
    _Float16* aggl = (_Float16*)alloc((size_t)n * 128 * 2);

    const int B = 256;
    const int nb = (n + B - 1) / B;
    const int rblocks = (n + 127) / 128;

    zero_i32<<<nb, B, 0, stream>>>(deg, n);
    fill_f32<<<nb, B, 0, stream>>>(out, bfc, n);
    deg_count_i<<<(e + B - 1) / B, B, 0, stream>>>(dst, deg, e);
    scan1<<<nb, B, 0, stream>>>(deg, excl, bsum, dinv, n);
    scale_x<<<((n * 25) + B - 1) / B, B, 0, stream>>>(
        (const float4*)x, dinv, (float4*)xs, n * 25);
    wprep<<<256, 256, 0, stream>>>(W1, W2, W1h, W1l, W2h, W2l);
    scan2<<<1, B, 0, stream>>>(bsum, nb, rowptr, n);
    scan3<<<nb, B, 0, stream>>>(excl, bsum, rowptr, cursor, n);
    csr_fill<<<(e + B - 1) / B, B, 0, stream>>>(src, dst, cursor, csr, e);

    // layer 1: pull-aggregate xs -> split-fp16 aggX
    pull_f100<<<(n + 3) / 4, 256, 0, stream>>>(xs, rowptr, csr, dinv, aggh, aggl, n);
    // fused GEMM1+GEMM2 -> chunk-major fp32 h2c (overwrites dead xs region)
    gemm12_fused<<<rblocks, 512, 0, stream>>>(aggh, aggl, W1h, W1l, W2h, W2l,
                                              b1, dinv, h2c, n);
    // layer-2 fused pull
    pull_c16_fused<<<8 * ((n + 63) / 64), 256, 0, stream>>>(
        h2c, rowptr, csr, dinv, b2, Wfc, out, n);
}